// Round 7
// baseline (898.103 us; speedup 1.0000x reference)
//
#include <hip/hip_runtime.h>
#include <hip/hip_bf16.h>

#define DEVI __device__ __forceinline__

typedef __attribute__((ext_vector_type(8))) __bf16 bf16x8;
typedef __attribute__((ext_vector_type(4))) float f32x4;
typedef __attribute__((ext_vector_type(4))) unsigned short u16x4;
typedef __attribute__((ext_vector_type(8))) unsigned short u16x8;

DEVI unsigned short f2bf(float f) {
  unsigned int u = __float_as_uint(f);
  u += 0x7FFFu + ((u >> 16) & 1u);   // RNE
  return (unsigned short)(u >> 16);
}
DEVI float bf2f(unsigned short u) {
  return __uint_as_float(((unsigned int)u) << 16);
}

#define GLD16(g, l) __builtin_amdgcn_global_load_lds(                      \
    (const __attribute__((address_space(1))) void*)(g),                    \
    (__attribute__((address_space(3))) void*)(l), 16, 0, 0)

// ---------------------------------------------------------------- helpers

__global__ __launch_bounds__(256) void cast_k(const float* __restrict__ in,
                                              unsigned short* __restrict__ out,
                                              int n4) {
  for (int i = blockIdx.x * 256 + threadIdx.x; i < n4; i += gridDim.x * 256) {
    f32x4 v = ((const f32x4*)in)[i];
    u16x4 o;
    o.x = f2bf(v.x); o.y = f2bf(v.y); o.z = f2bf(v.z); o.w = f2bf(v.w);
    ((u16x4*)out)[i] = o;
  }
}

// colnorm phase 1: partial column sumsq over a 64-row x 512-col tile.
__global__ __launch_bounds__(256) void colnorm1_k(const float* __restrict__ v,
                                                  float* __restrict__ part,
                                                  int cols) {
  const int tid = threadIdx.x;
  const int g = tid & 127;
  const int s = tid >> 7;
  const int c0 = blockIdx.x * 512;
  const int r0 = blockIdx.y * 64 + s * 32;
  const float* base = v + (size_t)r0 * cols + c0 + g * 4;
  f32x4 acc = {};
#pragma unroll 4
  for (int i = 0; i < 32; ++i) {
    f32x4 x = *(const f32x4*)(base + (size_t)i * cols);
    acc.x += x.x * x.x; acc.y += x.y * x.y;
    acc.z += x.z * x.z; acc.w += x.w * x.w;
  }
  __shared__ f32x4 red[256];
  red[tid] = acc;
  __syncthreads();
  if (s == 0) {
    f32x4 a = red[tid], b = red[tid + 128];
    f32x4 o;
    o.x = a.x + b.x; o.y = a.y + b.y; o.z = a.z + b.z; o.w = a.w + b.w;
    *(f32x4*)(part + (size_t)blockIdx.y * cols + c0 + g * 4) = o;
  }
}

// colnorm phase 2: s[c] = g[c] * rsqrt(sum_rc part[rc][c])
__global__ __launch_bounds__(256) void colnorm2_k(const float* __restrict__ part,
                                                  const float* __restrict__ g,
                                                  float* __restrict__ s,
                                                  int cols, int nrc) {
  const int c = blockIdx.x * 256 + threadIdx.x;
  float acc = 0.f;
  for (int i = 0; i < nrc; ++i) acc += part[(size_t)i * cols + c];
  s[c] = g[c] * rsqrtf(acc);
}

__global__ __launch_bounds__(256) void scale_cast_k(const float* __restrict__ in,
                                                    const float* __restrict__ s,
                                                    unsigned short* __restrict__ out,
                                                    int cols, int n4) {
  const int cmask4 = (cols >> 2) - 1;
  for (int i = blockIdx.x * 256 + threadIdx.x; i < n4; i += gridDim.x * 256) {
    f32x4 v = ((const f32x4*)in)[i];
    f32x4 sv = ((const f32x4*)s)[i & cmask4];
    u16x4 o;
    o.x = f2bf(v.x * sv.x); o.y = f2bf(v.y * sv.y);
    o.z = f2bf(v.z * sv.z); o.w = f2bf(v.w * sv.w);
    ((u16x4*)out)[i] = o;
  }
}

// LayerNorm: one block per row of 2048 fp32, out bf16
__global__ __launch_bounds__(256) void ln_k(const float* __restrict__ x,
                                            const float* __restrict__ g,
                                            const float* __restrict__ b,
                                            unsigned short* __restrict__ out) {
  const int tid = threadIdx.x, lane = tid & 63, wid = tid >> 6;
  const int row = blockIdx.x;
  const float* xr = x + (size_t)row * 2048;
  f32x4 a0 = ((const f32x4*)xr)[tid];
  f32x4 a1 = ((const f32x4*)xr)[tid + 256];
  float s = a0.x + a0.y + a0.z + a0.w + a1.x + a1.y + a1.z + a1.w;
  float ss = a0.x * a0.x + a0.y * a0.y + a0.z * a0.z + a0.w * a0.w +
             a1.x * a1.x + a1.y * a1.y + a1.z * a1.z + a1.w * a1.w;
#pragma unroll
  for (int m = 1; m < 64; m <<= 1) {
    s += __shfl_xor(s, m);
    ss += __shfl_xor(ss, m);
  }
  __shared__ float red[8];
  if (lane == 0) { red[wid] = s; red[4 + wid] = ss; }
  __syncthreads();
  s = red[0] + red[1] + red[2] + red[3];
  ss = red[4] + red[5] + red[6] + red[7];
  const float mu = s * (1.f / 2048.f);
  const float var = ss * (1.f / 2048.f) - mu * mu;
  const float rs = rsqrtf(var + 1e-5f);
  f32x4 g0 = ((const f32x4*)g)[tid], g1 = ((const f32x4*)g)[tid + 256];
  f32x4 b0 = ((const f32x4*)b)[tid], b1 = ((const f32x4*)b)[tid + 256];
  u16x4 o0, o1;
  o0.x = f2bf((a0.x - mu) * rs * g0.x + b0.x);
  o0.y = f2bf((a0.y - mu) * rs * g0.y + b0.y);
  o0.z = f2bf((a0.z - mu) * rs * g0.z + b0.z);
  o0.w = f2bf((a0.w - mu) * rs * g0.w + b0.w);
  o1.x = f2bf((a1.x - mu) * rs * g1.x + b1.x);
  o1.y = f2bf((a1.y - mu) * rs * g1.y + b1.y);
  o1.z = f2bf((a1.z - mu) * rs * g1.z + b1.z);
  o1.w = f2bf((a1.w - mu) * rs * g1.w + b1.w);
  unsigned short* orow = out + (size_t)row * 2048;
  *(u16x4*)(orow + 4 * tid) = o0;
  *(u16x4*)(orow + 1024 + 4 * tid) = o1;
}

// V transpose: V slice of qkv [4096][6144] (cols 4096+h*128..) -> vt [32][128][2048]
__global__ __launch_bounds__(256) void vtrans_k(const unsigned short* __restrict__ qkv,
                                                unsigned short* __restrict__ vt) {
  __shared__ unsigned short t[64][134];
  const int tid = threadIdx.x;
  const int bh = blockIdx.x >> 5, st = blockIdx.x & 31;
  const int b = bh >> 4, h = bh & 15;
  const unsigned short* vb = qkv + (size_t)(b * 2048 + st * 64) * 6144 + 4096 + h * 128;
#pragma unroll
  for (int i = 0; i < 4; ++i) {
    int f = tid + (i << 8);
    int row = f >> 4, c8 = f & 15;
    u16x8 x = *(const u16x8*)(vb + (size_t)row * 6144 + c8 * 8);
#pragma unroll
    for (int j = 0; j < 4; ++j) {
      unsigned int pk = ((unsigned int)x[2 * j + 1] << 16) | x[2 * j];
      *(unsigned int*)&t[row][c8 * 8 + 2 * j] = pk;
    }
  }
  __syncthreads();
  const int lane = tid & 63, wid = tid >> 6;
  unsigned short* ob = vt + ((size_t)bh << 18) + (st << 6);
#pragma unroll
  for (int j = 0; j < 32; ++j) {
    int d = (wid << 5) + j;
    ob[((size_t)d << 11) + lane] = t[lane][d];
  }
}

// split-K4 reduce: out = sum(bf16 parts 0..3) + bias + res (fp32)
__global__ __launch_bounds__(256) void g4red_k(const unsigned short* __restrict__ parts,
                                               const float* __restrict__ bias,
                                               const float* __restrict__ res,
                                               float* __restrict__ out, int n4) {
  const size_t PS = (size_t)4096 * 2048;
  for (int i = blockIdx.x * 256 + threadIdx.x; i < n4; i += gridDim.x * 256) {
    u16x4 a = ((const u16x4*)(parts))[i];
    u16x4 b = ((const u16x4*)(parts + PS))[i];
    u16x4 c = ((const u16x4*)(parts + 2 * PS))[i];
    u16x4 d = ((const u16x4*)(parts + 3 * PS))[i];
    f32x4 r = ((const f32x4*)res)[i];
    f32x4 bb = ((const f32x4*)bias)[i & 511];
    f32x4 o;
    o.x = bf2f(a.x) + bf2f(b.x) + bf2f(c.x) + bf2f(d.x) + r.x + bb.x;
    o.y = bf2f(a.y) + bf2f(b.y) + bf2f(c.y) + bf2f(d.y) + r.y + bb.y;
    o.z = bf2f(a.z) + bf2f(b.z) + bf2f(c.z) + bf2f(d.z) + r.z + bb.z;
    o.w = bf2f(a.w) + bf2f(b.w) + bf2f(c.w) + bf2f(d.w) + r.w + bb.w;
    ((f32x4*)out)[i] = o;
  }
}

// ---------------------------------------------------------------- GEMM params
struct GemmP {
  const unsigned short* A;
  const unsigned short* B;
  const float* bias;
  const float* res;
  float* outF;
  unsigned short* outH;
  int M, N, K;
};

// ---------------------------------------------------------------- 128^2 GEMM (2-phase)
// EPI: 0 = +bias -> bf16   1 = +bias+res -> fp32   5 = raw -> bf16 (split-K partial)
template <int EPI>
DEVI void gemm128_body(const GemmP& p, int m0, int n0, int k0, int nk) {
  const int tid = threadIdx.x, lane = tid & 63, wid = tid >> 6;
  const int K = p.K;
  const int wr = wid >> 1, wc = wid & 1;

  __shared__ __align__(16) unsigned short sA[2][4096];
  __shared__ __align__(16) unsigned short sB[2][4096];

  const int c0 = tid, c1 = tid + 256;
  const unsigned short* gA0 = p.A + (size_t)(m0 + (c0 >> 2)) * K + k0 + ((c0 & 3) << 3);
  const unsigned short* gA1 = p.A + (size_t)(m0 + (c1 >> 2)) * K + k0 + ((c1 & 3) << 3);
  const unsigned short* gB0 = p.B + (size_t)(n0 + (c0 >> 2)) * K + k0 + ((c0 & 3) << 3);
  const unsigned short* gB1 = p.B + (size_t)(n0 + (c1 >> 2)) * K + k0 + ((c1 & 3) << 3);
  const int l0 = wid << 9, l1 = (wid << 9) + 2048;

  f32x4 acc[4][4] = {};
  const int arow = (wr << 6) + (lane & 15);
  const int brow = (wc << 6) + (lane & 15);
  const int koff = (lane >> 4) << 3;

#define STAGE128(bufi, t) do { int ko = (t) << 5;       \
    GLD16(gA0 + ko, &sA[bufi][l0]);                     \
    GLD16(gA1 + ko, &sA[bufi][l1]);                     \
    GLD16(gB0 + ko, &sB[bufi][l0]);                     \
    GLD16(gB1 + ko, &sB[bufi][l1]); } while (0)

  STAGE128(0, 0);
  __syncthreads();
  int cur = 0;
  for (int t = 0; t < nk; ++t) {
    if (t + 1 < nk) STAGE128(cur ^ 1, t + 1);
    bf16x8 af[4], bfr[4];
#pragma unroll
    for (int i = 0; i < 4; ++i)
      af[i] = *(const bf16x8*)&sA[cur][(arow + (i << 4)) * 32 + koff];
#pragma unroll
    for (int i = 0; i < 4; ++i)
      bfr[i] = *(const bf16x8*)&sB[cur][(brow + (i << 4)) * 32 + koff];
#pragma unroll
    for (int i = 0; i < 4; ++i)
#pragma unroll
      for (int j = 0; j < 4; ++j)
        acc[i][j] = __builtin_amdgcn_mfma_f32_16x16x32_bf16(af[i], bfr[j], acc[i][j], 0, 0, 0);
    __syncthreads();
    cur ^= 1;
  }
#undef STAGE128

  const int rbase = m0 + (wr << 6) + ((lane >> 4) << 2);
  const int cbase = n0 + (wc << 6) + (lane & 15);
#pragma unroll
  for (int mi = 0; mi < 4; ++mi) {
#pragma unroll
    for (int ni = 0; ni < 4; ++ni) {
      const int col = cbase + (ni << 4);
#pragma unroll
      for (int r = 0; r < 4; ++r) {
        const int row = rbase + (mi << 4) + r;
        if constexpr (EPI == 0) {
          p.outH[(size_t)row * p.N + col] = f2bf(acc[mi][ni][r] + p.bias[col]);
        } else if constexpr (EPI == 1) {
          const size_t o = (size_t)row * p.N + col;
          p.outF[o] = acc[mi][ni][r] + p.bias[col] + p.res[o];
        } else {
          p.outH[(size_t)row * p.N + col] = f2bf(acc[mi][ni][r]);
        }
      }
    }
  }
}

// G1: M=4096,N=6144 -> nbm=32,nbn=48. Region/XCD = 32 rows x 6 cols, bm-fastest.
__global__ __launch_bounds__(256) void g1_qkv128(GemmP p) {
  const int x = blockIdx.x & 7, i = blockIdx.x >> 3;  // i in [0,192)
  const int bm = i & 31;
  const int bn = x * 6 + (i >> 5);
  gemm128_body<0>(p, bm << 7, bn << 7, 0, p.K >> 5);
}
// G2: M=4096,N=2048 -> nbm=32,nbn=16. Region/XCD = 8x8.
__global__ __launch_bounds__(256) void g2_proj128(GemmP p) {
  const int x = blockIdx.x & 7, i = blockIdx.x >> 3;  // i in [0,64)
  const int bm = (x >> 1) * 8 + (i >> 3);
  const int bn = (x & 1) * 8 + (i & 7);
  gemm128_body<1>(p, bm << 7, bn << 7, 0, p.K >> 5);
}
// G4 split-K4: 2048 blocks; partial (bf16) -> p.outH + ks*M*N
__global__ __launch_bounds__(256) void g4_splitk(GemmP p) {
  const int x = blockIdx.x & 7, i = blockIdx.x >> 3;  // i in [0,256)
  const int ks = i & 3, j = i >> 2;                   // j in [0,64)
  const int bm = (x >> 1) * 8 + (j >> 3);
  const int bn = (x & 1) * 8 + (j & 7);
  GemmP q = p;
  q.outH = p.outH + (size_t)ks * 4096 * 2048;
  gemm128_body<5>(q, bm << 7, bn << 7, ks << 11, 64);   // K-quarter = 2048
}

// ---------------------------------------------------------------- 256^2 tile common
DEVI void setup256(const GemmP& p, int m0, int n0,
                   const unsigned short*& gsA0, const unsigned short*& gsA1,
                   const unsigned short*& gsB0, const unsigned short*& gsB1) {
  const int tid = threadIdx.x;
  int r_[2], c_[2];
#pragma unroll
  for (int j = 0; j < 2; ++j) {
    int d = tid * 16 + j * 8192;
    int w = (d & 1023) ^ (((d >> 9) & 1) << 5);   // st_16x32 involution
    r_[j] = ((d >> 10) << 4) + (w >> 6);
    c_[j] = (w & 63) >> 1;
  }
  gsA0 = p.A + (size_t)(m0 + r_[0]) * p.K + c_[0];
  gsA1 = p.A + (size_t)(m0 + r_[1]) * p.K + c_[1];
  gsB0 = p.B + (size_t)(n0 + r_[0]) * p.K + c_[0];
  gsB1 = p.B + (size_t)(n0 + r_[1]) * p.K + c_[1];
}

// epilogue: +bias, fast-GELU -> bf16
DEVI void epi256g(const GemmP& p, f32x4 (&acc)[8][4], int m0, int n0) {
  const int lane = threadIdx.x & 63, wid = threadIdx.x >> 6;
  const int wr = wid >> 2, wc = wid & 3;
  const int lr = lane & 15, lk = lane >> 4;
  const int rbase = m0 + wr * 128 + (lk << 2);
  const int cbase = n0 + wc * 64 + lr;
#pragma unroll
  for (int m = 0; m < 8; ++m) {
#pragma unroll
    for (int n = 0; n < 4; ++n) {
      const int col = cbase + (n << 4);
      const float bb = p.bias[col];
#pragma unroll
      for (int r = 0; r < 4; ++r) {
        const int row = rbase + (m << 4) + r;
        float v = acc[m][n][r] + bb;
        float y = 0.7978845608028654f * (v + 0.044715f * v * v * v);
        float u = __expf(2.f * y);
        float gl = (y > 40.f) ? v : v * (u / (u + 1.f));
        p.outH[(size_t)row * p.N + col] = f2bf(gl);
      }
    }
  }
}

// ---------------------------------------------------------------- 256^2 8-phase (A arm)
DEVI void gemm8p_body(const GemmP& p, unsigned short* lds_raw, int m0, int n0) {
  const int tid = threadIdx.x, lane = tid & 63, wid = tid >> 6;
  const int wr = wid >> 2, wc = wid & 3;
  const int lr = lane & 15, lk = lane >> 4;
  const int fb = (lr * 64 + lk * 16) ^ ((lr & 8) << 2);

  const unsigned short *gsA0, *gsA1, *gsB0, *gsB1;
  setup256(p, m0, n0, gsA0, gsA1, gsB0, gsB1);

#define STAGE_A8(b, kt) do { unsigned short* _d = lds_raw + ((b) << 14);       \
    GLD16(gsA0 + ((size_t)(kt) << 5), _d + (tid << 3));                        \
    GLD16(gsA1 + ((size_t)(kt) << 5), _d + 4096 + (tid << 3)); } while (0)
#define STAGE_B8(b, kt) do { unsigned short* _d = lds_raw + ((b) << 14) + 8192;\
    GLD16(gsB0 + ((size_t)(kt) << 5), _d + (tid << 3));                        \
    GLD16(gsB1 + ((size_t)(kt) << 5), _d + 4096 + (tid << 3)); } while (0)

  f32x4 acc[8][4] = {};
  const int NK = p.K >> 5;

  STAGE_A8(0, 0); STAGE_B8(0, 0);
  STAGE_A8(1, 1); STAGE_B8(1, 1);
  STAGE_A8(2, 2); STAGE_B8(2, 2);
  asm volatile("s_waitcnt vmcnt(8)" ::: "memory");
  __builtin_amdgcn_s_barrier();

  for (int t = 0; t < NK; ++t) {
    const int bi = t & 3;
    const char* tA = (const char*)(lds_raw + (bi << 14));
    const char* tB = (const char*)(lds_raw + (bi << 14) + 8192);
    bf16x8 a_[4], b_[4];
#pragma unroll
    for (int n = 0; n < 4; ++n)
      b_[n] = *(const bf16x8*)(tB + (((wc << 2) + n) << 10) + fb);
#pragma unroll
    for (int m = 0; m < 4; ++m)
      a_[m] = *(const bf16x8*)(tA + (((wr << 3) + m) << 10) + fb);
    if (t + 3 < NK) STAGE_A8((t + 3) & 3, t + 3);
    __builtin_amdgcn_s_barrier();
    asm volatile("s_waitcnt lgkmcnt(0)" ::: "memory");
    __builtin_amdgcn_sched_barrier(0);
    __builtin_amdgcn_s_setprio(1);
#pragma unroll
    for (int m = 0; m < 4; ++m)
#pragma unroll
      for (int n = 0; n < 4; ++n)
        acc[m][n] = __builtin_amdgcn_mfma_f32_16x16x32_bf16(a_[m], b_[n], acc[m][n], 0, 0, 0);
    __builtin_amdgcn_s_setprio(0);
    __builtin_amdgcn_s_barrier();
#pragma unroll
    for (int m = 0; m < 4; ++m)
      a_[m] = *(const bf16x8*)(tA + (((wr << 3) + 4 + m) << 10) + fb);
    if (t + 3 < NK) STAGE_B8((t + 3) & 3, t + 3);
    if (t + 3 < NK)      asm volatile("s_waitcnt vmcnt(8)" ::: "memory");
    else if (t + 2 < NK) asm volatile("s_waitcnt vmcnt(4)" ::: "memory");
    else if (t + 1 < NK) asm volatile("s_waitcnt vmcnt(0)" ::: "memory");
    __builtin_amdgcn_s_barrier();
    asm volatile("s_waitcnt lgkmcnt(0)" ::: "memory");
    __builtin_amdgcn_sched_barrier(0);
    __builtin_amdgcn_s_setprio(1);
#pragma unroll
    for (int m = 0; m < 4; ++m)
#pragma unroll
      for (int n = 0; n < 4; ++n)
        acc[4 + m][n] = __builtin_amdgcn_mfma_f32_16x16x32_bf16(a_[m], b_[n], acc[4 + m][n], 0, 0, 0);
    __builtin_amdgcn_s_setprio(0);
    __builtin_amdgcn_s_barrier();
  }
#undef STAGE_A8
#undef STAGE_B8
  epi256g(p, acc, m0, n0);
}

// ---------------------------------------------------------------- 256^2 2-phase (B arm)
DEVI void gemm2p_body(const GemmP& p, unsigned short* lds_raw, int m0, int n0) {
  const int tid = threadIdx.x, lane = tid & 63, wid = tid >> 6;
  const int wr = wid >> 2, wc = wid & 3;
  const int lr = lane & 15, lk = lane >> 4;
  const int fb = (lr * 64 + lk * 16) ^ ((lr & 8) << 2);

  const unsigned short *gsA0, *gsA1, *gsB0, *gsB1;
  setup256(p, m0, n0, gsA0, gsA1, gsB0, gsB1);

#define STG2(b, kt) do { unsigned short* _d = lds_raw + ((b) << 14);     \
    GLD16(gsA0 + ((size_t)(kt) << 5), _d + (tid << 3));                  \
    GLD16(gsA1 + ((size_t)(kt) << 5), _d + 4096 + (tid << 3));           \
    GLD16(gsB0 + ((size_t)(kt) << 5), _d + 8192 + (tid << 3));           \
    GLD16(gsB1 + ((size_t)(kt) << 5), _d + 12288 + (tid << 3)); } while (0)

  f32x4 acc[8][4] = {};
  const int NK = p.K >> 5;
  STG2(0, 0);
  __syncthreads();
  int cur = 0;
  for (int t = 0; t < NK; ++t) {
    if (t + 1 < NK) STG2(cur ^ 1, t + 1);
    const char* tA = (const char*)(lds_raw + (cur << 14));
    const char* tB = tA + 16384;
    bf16x8 a_[8], b_[4];
#pragma unroll
    for (int n = 0; n < 4; ++n)
      b_[n] = *(const bf16x8*)(tB + (((wc << 2) + n) << 10) + fb);
#pragma unroll
    for (int m = 0; m < 8; ++m)
      a_[m] = *(const bf16x8*)(tA + (((wr << 3) + m) << 10) + fb);
#pragma unroll
    for (int m = 0; m < 8; ++m)
#pragma unroll
      for (int n = 0; n < 4; ++n)
        acc[m][n] = __builtin_amdgcn_mfma_f32_16x16x32_bf16(a_[m], b_[n], acc[m][n], 0, 0, 0);
    __syncthreads();
    cur ^= 1;
  }
#undef STG2
  epi256g(p, acc, m0, n0);
}

// G3a: rows [0,2048), 8-phase. Region 4x8 per XCD
__global__ __launch_bounds__(512, 2) void g3a_fc8p(GemmP p) {
  extern __shared__ unsigned short lds_raw[];
  const int x = blockIdx.x & 7, i = blockIdx.x >> 3;
  const int bm = (x >> 2) * 4 + (i >> 3);
  const int bn = (x & 3) * 8 + (i & 7);
  gemm8p_body(p, lds_raw, bm << 8, bn << 8);
}
// G3b: rows [2048,4096), 2-phase (A/B control)
__global__ __launch_bounds__(512, 2) void g3b_fc2p(GemmP p) {
  extern __shared__ unsigned short lds_raw[];
  const int x = blockIdx.x & 7, i = blockIdx.x >> 3;
  const int bm = (x >> 2) * 4 + (i >> 3);
  const int bn = (x & 3) * 8 + (i & 7);
  gemm2p_body(p, lds_raw, 2048 + (bm << 8), bn << 8);
}

// ---------------------------------------------------------------- attention
// Q,K read from unified qkv [4096][6144]; V^T [32][128][2048]; O bf16 [4096][2048].
__global__ __launch_bounds__(256) void attn_k(const unsigned short* __restrict__ qkv,
                                              const unsigned short* __restrict__ Vt,
                                              unsigned short* __restrict__ O) {
  const int tid = threadIdx.x, lane = tid & 63, wid = tid >> 6;
  const int bid = blockIdx.x;
  const int pos = bid >> 3;
  const int bh = (bid & 7) * 4 + (pos >> 5);
  const int qt = pos & 31;
  const int q0 = qt * 64 + wid * 16;
  const int b = bh >> 4, h = bh & 15;

  __shared__ __align__(16) unsigned short sK[64 * 128];
  __shared__ __align__(16) unsigned short sV[128 * 64];
  __shared__ __align__(16) unsigned short sP[4][16 * 72];

  const unsigned short* Qb = qkv + (size_t)(b * 2048) * 6144 + h * 128;
  const unsigned short* Kb = qkv + (size_t)(b * 2048) * 6144 + 2048 + h * 128;
  const unsigned short* Vb = Vt + ((size_t)bh << 18);

  bf16x8 qf[4];
  {
    const unsigned short* qp = Qb + (size_t)(q0 + (lane & 15)) * 6144 + ((lane >> 4) << 3);
#pragma unroll
    for (int kk = 0; kk < 4; ++kk) qf[kk] = *(const bf16x8*)(qp + kk * 32);
  }

  int koffs[4], voffs[4];
#pragma unroll
  for (int i = 0; i < 4; ++i) {
    const int c = tid + (i << 8);
    const int kv = c >> 4, jj = c & 15;
    const int js = (jj & 8) | ((jj ^ kv) & 7);
    koffs[i] = kv * 6144 + (js << 3);
    const int d = c >> 3, j2 = c & 7;
    const int js2 = j2 ^ (d & 7);
    voffs[i] = d * 2048 + (js2 << 3);
  }
  u16x8 kreg[4], vreg[4];
  auto PREF = [&](int kt) {
    const int kv0 = kt << 6;
    const unsigned short* kb = Kb + (size_t)kv0 * 6144;
#pragma unroll
    for (int i = 0; i < 4; ++i) {
      kreg[i] = *(const u16x8*)(kb + koffs[i]);
      vreg[i] = *(const u16x8*)(Vb + kv0 + voffs[i]);
    }
  };

  f32x4 oacc[8] = {};
  float mrun = -3e38f, lrun = 0.f;
  PREF(0);

  for (int kt = 0; kt < 32; ++kt) {
#pragma unroll
    for (int i = 0; i < 4; ++i) {
      const int c8 = (tid + (i << 8)) << 3;
      *(u16x8*)&sK[c8] = kreg[i];
      *(u16x8*)&sV[c8] = vreg[i];
    }
    __syncthreads();
    if (kt + 1 < 32) PREF(kt + 1);

    f32x4 sc[4] = {};
    __builtin_amdgcn_s_setprio(1);
#pragma unroll
    for (int ti = 0; ti < 4; ++ti) {
#pragma unroll
      for (int kk = 0; kk < 4; ++kk) {
        const int row = (ti << 4) + (lane & 15);
        int bo = (row << 8) + (kk << 6) + ((lane >> 4) << 4);
        bo ^= (row & 7) << 4;
        bf16x8 kf = *(const bf16x8*)((const char*)sK + bo);
        sc[ti] = __builtin_amdgcn_mfma_f32_16x16x32_bf16(kf, qf[kk], sc[ti], 0, 0, 0);
      }
    }
    __builtin_amdgcn_s_setprio(0);

    float pv[16];
    float mx = -3e38f;
#pragma unroll
    for (int ti = 0; ti < 4; ++ti)
#pragma unroll
      for (int r = 0; r < 4; ++r) {
        float x = sc[ti][r] * 0.08838834764831845f;
        pv[(ti << 2) + r] = x;
        mx = fmaxf(mx, x);
      }
    mx = fmaxf(mx, __shfl_xor(mx, 16));
    mx = fmaxf(mx, __shfl_xor(mx, 32));

    float corr = 1.f;
    if (!__all(mx - mrun <= 8.f)) {
      const float mnew = fmaxf(mrun, mx);
      corr = __expf(mrun - mnew);
      mrun = mnew;
      float fr[4];
#pragma unroll
      for (int r = 0; r < 4; ++r) fr[r] = __shfl(corr, ((lane >> 4) << 2) + r);
#pragma unroll
      for (int di = 0; di < 8; ++di)
#pragma unroll
        for (int r = 0; r < 4; ++r) oacc[di][r] *= fr[r];
    }
    float psum = 0.f;
#pragma unroll
    for (int i2 = 0; i2 < 16; ++i2) {
      float e = __expf(pv[i2] - mrun);
      pv[i2] = e;
      psum += e;
    }
    psum += __shfl_xor(psum, 16);
    psum += __shfl_xor(psum, 32);
    lrun = lrun * corr + psum;

    unsigned short* prow = &sP[wid][(lane & 15) * 72];
#pragma unroll
    for (int ti = 0; ti < 4; ++ti) {
      u16x4 w4;
      w4.x = f2bf(pv[(ti << 2) + 0]);
      w4.y = f2bf(pv[(ti << 2) + 1]);
      w4.z = f2bf(pv[(ti << 2) + 2]);
      w4.w = f2bf(pv[(ti << 2) + 3]);
      *(u16x4*)&prow[(ti << 4) + ((lane >> 4) << 2)] = w4;
    }

    __builtin_amdgcn_s_setprio(1);
#pragma unroll
    for (int di = 0; di < 8; ++di) {
#pragma unroll
      for (int ks = 0; ks < 2; ++ks) {
        bf16x8 pf = *(const bf16x8*)((const char*)&sP[wid][0] +
                                     (lane & 15) * 144 + (ks << 6) + ((lane >> 4) << 4));
        const int dr = (di << 4) + (lane & 15);
        int bo = (dr << 7) + (ks << 6) + ((lane >> 4) << 4);
        bo ^= (dr & 7) << 4;
        bf16x8 vf = *(const bf16x8*)((const char*)sV + bo);
        oacc[di] = __builtin_amdgcn_mfma_f32_16x16x32_bf16(pf, vf, oacc[di], 0, 0, 0);
      }
    }
    __builtin_amdgcn_s_setprio(0);
    __syncthreads();
  }

  float il[4];
#pragma unroll
  for (int r = 0; r < 4; ++r) il[r] = 1.f / __shfl(lrun, ((lane >> 4) << 2) + r);
  const size_t obase = ((size_t)(b * 2048 + q0)) * 2048 + h * 128;
#pragma unroll
  for (int di = 0; di < 8; ++di)
#pragma unroll
    for (int r = 0; r < 4; ++r) {
      const size_t o = obase + (size_t)(((lane >> 4) << 2) + r) * 2048 + (di << 4) + (lane & 15);
      O[o] = f2bf(oacc[di][r] * il[r]);
    }
}

// ---------------------------------------------------------------- launch

extern "C" void kernel_launch(void* const* d_in, const int* in_sizes, int n_in,
                              void* d_out, int out_size, void* d_ws, size_t ws_size,
                              hipStream_t stream) {
  (void)in_sizes; (void)n_in; (void)out_size; (void)ws_size;
  const float* hidden = (const float*)d_in[0];
  const float* ln1_g = (const float*)d_in[1];
  const float* ln1_b = (const float*)d_in[2];
  const float* w_qkv = (const float*)d_in[3];
  const float* b_qkv = (const float*)d_in[4];
  const float* apv = (const float*)d_in[5];
  const float* apg = (const float*)d_in[6];
  const float* apb = (const float*)d_in[7];
  // d_in[8] emotion_bias: softmax-invariant -> dropped (exact)
  const float* ln2_g = (const float*)d_in[9];
  const float* ln2_b = (const float*)d_in[10];
  const float* w_fc = (const float*)d_in[11];
  const float* b_fc = (const float*)d_in[12];
  const float* mpv = (const float*)d_in[13];
  const float* mpg = (const float*)d_in[14];
  const float* mpb = (const float*)d_in[15];

  char* w = (char*)d_ws;
  const size_t MBs = 1ull << 20;
  // lifetimes:  [0,16) xln (LN1->G1) then [0,32) hidden2 (G2->end)
  //             [32,48) vtbuf (vtrans->attn) then [32,96) hbuf (G3->G4)
  //             [96,144) qkv (G1->attn) then [96,128) wfc_bf (cast->G3),
  //             [128,144) xln2 (LN2->G3); [144,160) attn_out (attn->G2)
  //             [96,160) g4 bf16 partials (G4->reduce)
  //             [160,184) wqkv_bf (->G1) then [160,192) w2_bf (->G4)
  //             [192,200) wproj_bf; [200+] small scratch
  unsigned short* xln = (unsigned short*)(w + 0);
  float* hidden2 = (float*)(w + 0);
  unsigned short* vtbuf = (unsigned short*)(w + 32 * MBs);
  unsigned short* hbuf = (unsigned short*)(w + 32 * MBs);
  unsigned short* qkv = (unsigned short*)(w + 96 * MBs);
  unsigned short* wfc_bf = (unsigned short*)(w + 96 * MBs);
  unsigned short* xln2 = (unsigned short*)(w + 128 * MBs);
  unsigned short* attn_out = (unsigned short*)(w + 144 * MBs);
  unsigned short* partH = (unsigned short*)(w + 96 * MBs);
  unsigned short* wqkv_bf = (unsigned short*)(w + 160 * MBs);
  unsigned short* w2_bf = (unsigned short*)(w + 160 * MBs);
  unsigned short* wproj_bf = (unsigned short*)(w + 192 * MBs);
  float* s_attn = (float*)(w + 200 * MBs);
  float* s_mlp = (float*)(w + 200 * MBs + 32768);
  float* part_attn = (float*)(w + 201 * MBs);
  float* part_mlp = (float*)(w + 202 * MBs);

  hipFuncSetAttribute((const void*)g3a_fc8p, hipFuncAttributeMaxDynamicSharedMemorySize, 131072);
  hipFuncSetAttribute((const void*)g3b_fc2p, hipFuncAttributeMaxDynamicSharedMemorySize, 65536);

  // weight prep
  cast_k<<<2048, 256, 0, stream>>>(w_qkv, wqkv_bf, (6144 * 2048) / 4);
  colnorm1_k<<<dim3(4, 32), 256, 0, stream>>>(apv, part_attn, 2048);
  colnorm2_k<<<8, 256, 0, stream>>>(part_attn, apg, s_attn, 2048, 32);
  scale_cast_k<<<2048, 256, 0, stream>>>(apv, s_attn, wproj_bf, 2048, (2048 * 2048) / 4);
  colnorm1_k<<<dim3(16, 32), 256, 0, stream>>>(mpv, part_mlp, 8192);
  colnorm2_k<<<32, 256, 0, stream>>>(part_mlp, mpg, s_mlp, 8192, 32);

  // LN1 -> xln (bf16)
  ln_k<<<4096, 256, 0, stream>>>(hidden, ln1_g, ln1_b, xln);

  // GEMM1 (128^2, coalesced unified-qkv epilogue): qkv = xln @ w_qkv^T + b
  GemmP p1 = {xln, wqkv_bf, b_qkv, nullptr, nullptr, qkv, 4096, 6144, 2048};
  g1_qkv128<<<1536, 256, 0, stream>>>(p1);

  // V slice of qkv -> V^T
  vtrans_k<<<1024, 256, 0, stream>>>(qkv, vtbuf);

  // attention (reads Q,K from qkv) -> attn_out
  attn_k<<<1024, 256, 0, stream>>>(qkv, vtbuf, attn_out);

  // weight casts for MLP (into regions dead after attn / G1)
  cast_k<<<2048, 256, 0, stream>>>(w_fc, wfc_bf, (8192 * 2048) / 4);
  scale_cast_k<<<4096, 256, 0, stream>>>(mpv, s_mlp, w2_bf, 8192, (2048 * 8192) / 4);

  // GEMM2 (128^2): hidden2 = attn_out @ w_proj^T + b + hidden
  GemmP p2 = {attn_out, wproj_bf, apb, hidden, hidden2, nullptr, 4096, 2048, 2048};
  g2_proj128<<<512, 256, 0, stream>>>(p2);

  // LN2 -> xln2
  ln_k<<<4096, 256, 0, stream>>>(hidden2, ln2_g, ln2_b, xln2);

  // GEMM3 A/B experiment: rows 0-2047 8-phase, rows 2048-4095 2-phase
  GemmP p3 = {xln2, wfc_bf, b_fc, nullptr, nullptr, hbuf, 4096, 8192, 2048};
  g3a_fc8p<<<256, 512, 131072, stream>>>(p3);
  g3b_fc2p<<<256, 512, 65536, stream>>>(p3);

  // GEMM4 split-K4 (2048 blocks, bf16 partials) -> fused reduce
  GemmP p4 = {hbuf, w2_bf, mpb, nullptr, nullptr, partH, 4096, 2048, 8192};
  g4_splitk<<<2048, 256, 0, stream>>>(p4);
  g4red_k<<<2048, 256, 0, stream>>>(partH, mpb, hidden2, (float*)d_out,
                                    (4096 * 2048) / 4);
}

// Round 8
// 895.480 us; speedup vs baseline: 1.0029x; 1.0029x over previous
//
#include <hip/hip_runtime.h>
#include <hip/hip_bf16.h>

#define DEVI __device__ __forceinline__

typedef __attribute__((ext_vector_type(8))) __bf16 bf16x8;
typedef __attribute__((ext_vector_type(4))) float f32x4;
typedef __attribute__((ext_vector_type(4))) unsigned short u16x4;
typedef __attribute__((ext_vector_type(8))) unsigned short u16x8;

DEVI unsigned short f2bf(float f) {
  unsigned int u = __float_as_uint(f);
  u += 0x7FFFu + ((u >> 16) & 1u);   // RNE
  return (unsigned short)(u >> 16);
}
DEVI float bf2f(unsigned short u) {
  return __uint_as_float(((unsigned int)u) << 16);
}

#define GLD16(g, l) __builtin_amdgcn_global_load_lds(                      \
    (const __attribute__((address_space(1))) void*)(g),                    \
    (__attribute__((address_space(3))) void*)(l), 16, 0, 0)

// ---------------------------------------------------------------- helpers

__global__ __launch_bounds__(256) void cast_k(const float* __restrict__ in,
                                              unsigned short* __restrict__ out,
                                              int n4) {
  for (int i = blockIdx.x * 256 + threadIdx.x; i < n4; i += gridDim.x * 256) {
    f32x4 v = ((const f32x4*)in)[i];
    u16x4 o;
    o.x = f2bf(v.x); o.y = f2bf(v.y); o.z = f2bf(v.z); o.w = f2bf(v.w);
    ((u16x4*)out)[i] = o;
  }
}

// colnorm phase 1: partial column sumsq over a 64-row x 512-col tile.
__global__ __launch_bounds__(256) void colnorm1_k(const float* __restrict__ v,
                                                  float* __restrict__ part,
                                                  int cols) {
  const int tid = threadIdx.x;
  const int g = tid & 127;
  const int s = tid >> 7;
  const int c0 = blockIdx.x * 512;
  const int r0 = blockIdx.y * 64 + s * 32;
  const float* base = v + (size_t)r0 * cols + c0 + g * 4;
  f32x4 acc = {};
#pragma unroll 4
  for (int i = 0; i < 32; ++i) {
    f32x4 x = *(const f32x4*)(base + (size_t)i * cols);
    acc.x += x.x * x.x; acc.y += x.y * x.y;
    acc.z += x.z * x.z; acc.w += x.w * x.w;
  }
  __shared__ f32x4 red[256];
  red[tid] = acc;
  __syncthreads();
  if (s == 0) {
    f32x4 a = red[tid], b = red[tid + 128];
    f32x4 o;
    o.x = a.x + b.x; o.y = a.y + b.y; o.z = a.z + b.z; o.w = a.w + b.w;
    *(f32x4*)(part + (size_t)blockIdx.y * cols + c0 + g * 4) = o;
  }
}

// colnorm phase 2: s[c] = g[c] * rsqrt(sum_rc part[rc][c])
__global__ __launch_bounds__(256) void colnorm2_k(const float* __restrict__ part,
                                                  const float* __restrict__ g,
                                                  float* __restrict__ s,
                                                  int cols, int nrc) {
  const int c = blockIdx.x * 256 + threadIdx.x;
  float acc = 0.f;
  for (int i = 0; i < nrc; ++i) acc += part[(size_t)i * cols + c];
  s[c] = g[c] * rsqrtf(acc);
}

__global__ __launch_bounds__(256) void scale_cast_k(const float* __restrict__ in,
                                                    const float* __restrict__ s,
                                                    unsigned short* __restrict__ out,
                                                    int cols, int n4) {
  const int cmask4 = (cols >> 2) - 1;
  for (int i = blockIdx.x * 256 + threadIdx.x; i < n4; i += gridDim.x * 256) {
    f32x4 v = ((const f32x4*)in)[i];
    f32x4 sv = ((const f32x4*)s)[i & cmask4];
    u16x4 o;
    o.x = f2bf(v.x * sv.x); o.y = f2bf(v.y * sv.y);
    o.z = f2bf(v.z * sv.z); o.w = f2bf(v.w * sv.w);
    ((u16x4*)out)[i] = o;
  }
}

// LayerNorm: one block per row of 2048 fp32, out bf16
__global__ __launch_bounds__(256) void ln_k(const float* __restrict__ x,
                                            const float* __restrict__ g,
                                            const float* __restrict__ b,
                                            unsigned short* __restrict__ out) {
  const int tid = threadIdx.x, lane = tid & 63, wid = tid >> 6;
  const int row = blockIdx.x;
  const float* xr = x + (size_t)row * 2048;
  f32x4 a0 = ((const f32x4*)xr)[tid];
  f32x4 a1 = ((const f32x4*)xr)[tid + 256];
  float s = a0.x + a0.y + a0.z + a0.w + a1.x + a1.y + a1.z + a1.w;
  float ss = a0.x * a0.x + a0.y * a0.y + a0.z * a0.z + a0.w * a0.w +
             a1.x * a1.x + a1.y * a1.y + a1.z * a1.z + a1.w * a1.w;
#pragma unroll
  for (int m = 1; m < 64; m <<= 1) {
    s += __shfl_xor(s, m);
    ss += __shfl_xor(ss, m);
  }
  __shared__ float red[8];
  if (lane == 0) { red[wid] = s; red[4 + wid] = ss; }
  __syncthreads();
  s = red[0] + red[1] + red[2] + red[3];
  ss = red[4] + red[5] + red[6] + red[7];
  const float mu = s * (1.f / 2048.f);
  const float var = ss * (1.f / 2048.f) - mu * mu;
  const float rs = rsqrtf(var + 1e-5f);
  f32x4 g0 = ((const f32x4*)g)[tid], g1 = ((const f32x4*)g)[tid + 256];
  f32x4 b0 = ((const f32x4*)b)[tid], b1 = ((const f32x4*)b)[tid + 256];
  u16x4 o0, o1;
  o0.x = f2bf((a0.x - mu) * rs * g0.x + b0.x);
  o0.y = f2bf((a0.y - mu) * rs * g0.y + b0.y);
  o0.z = f2bf((a0.z - mu) * rs * g0.z + b0.z);
  o0.w = f2bf((a0.w - mu) * rs * g0.w + b0.w);
  o1.x = f2bf((a1.x - mu) * rs * g1.x + b1.x);
  o1.y = f2bf((a1.y - mu) * rs * g1.y + b1.y);
  o1.z = f2bf((a1.z - mu) * rs * g1.z + b1.z);
  o1.w = f2bf((a1.w - mu) * rs * g1.w + b1.w);
  unsigned short* orow = out + (size_t)row * 2048;
  *(u16x4*)(orow + 4 * tid) = o0;
  *(u16x4*)(orow + 1024 + 4 * tid) = o1;
}

// V transpose: V slice of qkv [4096][6144] -> vt [32][128][2048]
__global__ __launch_bounds__(256) void vtrans_k(const unsigned short* __restrict__ qkv,
                                                unsigned short* __restrict__ vt) {
  __shared__ unsigned short t[64][134];
  const int tid = threadIdx.x;
  const int bh = blockIdx.x >> 5, st = blockIdx.x & 31;
  const int b = bh >> 4, h = bh & 15;
  const unsigned short* vb = qkv + (size_t)(b * 2048 + st * 64) * 6144 + 4096 + h * 128;
#pragma unroll
  for (int i = 0; i < 4; ++i) {
    int f = tid + (i << 8);
    int row = f >> 4, c8 = f & 15;
    u16x8 x = *(const u16x8*)(vb + (size_t)row * 6144 + c8 * 8);
#pragma unroll
    for (int j = 0; j < 4; ++j) {
      unsigned int pk = ((unsigned int)x[2 * j + 1] << 16) | x[2 * j];
      *(unsigned int*)&t[row][c8 * 8 + 2 * j] = pk;
    }
  }
  __syncthreads();
  const int lane = tid & 63, wid = tid >> 6;
  unsigned short* ob = vt + ((size_t)bh << 18) + (st << 6);
#pragma unroll
  for (int j = 0; j < 32; ++j) {
    int d = (wid << 5) + j;
    ob[((size_t)d << 11) + lane] = t[lane][d];
  }
}

// split-K2 reduce: out = part0 + part1 (bf16) + bias + res (fp32)
__global__ __launch_bounds__(256) void g4red_k(const unsigned short* __restrict__ parts,
                                               const float* __restrict__ bias,
                                               const float* __restrict__ res,
                                               float* __restrict__ out, int n4) {
  const size_t PS = (size_t)4096 * 2048;
  for (int i = blockIdx.x * 256 + threadIdx.x; i < n4; i += gridDim.x * 256) {
    u16x4 a = ((const u16x4*)(parts))[i];
    u16x4 b = ((const u16x4*)(parts + PS))[i];
    f32x4 r = ((const f32x4*)res)[i];
    f32x4 bb = ((const f32x4*)bias)[i & 511];
    f32x4 o;
    o.x = bf2f(a.x) + bf2f(b.x) + r.x + bb.x;
    o.y = bf2f(a.y) + bf2f(b.y) + r.y + bb.y;
    o.z = bf2f(a.z) + bf2f(b.z) + r.z + bb.z;
    o.w = bf2f(a.w) + bf2f(b.w) + r.w + bb.w;
    ((f32x4*)out)[i] = o;
  }
}

// ---------------------------------------------------------------- GEMM params
struct GemmP {
  const unsigned short* A;
  const unsigned short* B;
  const float* bias;
  const float* res;
  float* outF;
  unsigned short* outH;
  int M, N, K;
};

// ---------------------------------------------------------------- 128^2 GEMM (2-phase)
// EPI: 0 = +bias -> bf16   1 = +bias+res -> fp32   5 = raw -> bf16 (split-K partial)
template <int EPI>
DEVI void gemm128_body(const GemmP& p, int m0, int n0, int k0, int nk) {
  const int tid = threadIdx.x, lane = tid & 63, wid = tid >> 6;
  const int K = p.K;
  const int wr = wid >> 1, wc = wid & 1;

  __shared__ __align__(16) unsigned short sA[2][4096];
  __shared__ __align__(16) unsigned short sB[2][4096];

  const int c0 = tid, c1 = tid + 256;
  const unsigned short* gA0 = p.A + (size_t)(m0 + (c0 >> 2)) * K + k0 + ((c0 & 3) << 3);
  const unsigned short* gA1 = p.A + (size_t)(m0 + (c1 >> 2)) * K + k0 + ((c1 & 3) << 3);
  const unsigned short* gB0 = p.B + (size_t)(n0 + (c0 >> 2)) * K + k0 + ((c0 & 3) << 3);
  const unsigned short* gB1 = p.B + (size_t)(n0 + (c1 >> 2)) * K + k0 + ((c1 & 3) << 3);
  const int l0 = wid << 9, l1 = (wid << 9) + 2048;

  f32x4 acc[4][4] = {};
  const int arow = (wr << 6) + (lane & 15);
  const int brow = (wc << 6) + (lane & 15);
  const int koff = (lane >> 4) << 3;

#define STAGE128(bufi, t) do { int ko = (t) << 5;       \
    GLD16(gA0 + ko, &sA[bufi][l0]);                     \
    GLD16(gA1 + ko, &sA[bufi][l1]);                     \
    GLD16(gB0 + ko, &sB[bufi][l0]);                     \
    GLD16(gB1 + ko, &sB[bufi][l1]); } while (0)

  STAGE128(0, 0);
  __syncthreads();
  int cur = 0;
  for (int t = 0; t < nk; ++t) {
    if (t + 1 < nk) STAGE128(cur ^ 1, t + 1);
    bf16x8 af[4], bfr[4];
#pragma unroll
    for (int i = 0; i < 4; ++i)
      af[i] = *(const bf16x8*)&sA[cur][(arow + (i << 4)) * 32 + koff];
#pragma unroll
    for (int i = 0; i < 4; ++i)
      bfr[i] = *(const bf16x8*)&sB[cur][(brow + (i << 4)) * 32 + koff];
#pragma unroll
    for (int i = 0; i < 4; ++i)
#pragma unroll
      for (int j = 0; j < 4; ++j)
        acc[i][j] = __builtin_amdgcn_mfma_f32_16x16x32_bf16(af[i], bfr[j], acc[i][j], 0, 0, 0);
    __syncthreads();
    cur ^= 1;
  }
#undef STAGE128

  const int rbase = m0 + (wr << 6) + ((lane >> 4) << 2);
  const int cbase = n0 + (wc << 6) + (lane & 15);
#pragma unroll
  for (int mi = 0; mi < 4; ++mi) {
#pragma unroll
    for (int ni = 0; ni < 4; ++ni) {
      const int col = cbase + (ni << 4);
#pragma unroll
      for (int r = 0; r < 4; ++r) {
        const int row = rbase + (mi << 4) + r;
        if constexpr (EPI == 0) {
          p.outH[(size_t)row * p.N + col] = f2bf(acc[mi][ni][r] + p.bias[col]);
        } else if constexpr (EPI == 1) {
          const size_t o = (size_t)row * p.N + col;
          p.outF[o] = acc[mi][ni][r] + p.bias[col] + p.res[o];
        } else {
          p.outH[(size_t)row * p.N + col] = f2bf(acc[mi][ni][r]);
        }
      }
    }
  }
}

// G1: M=4096,N=6144 -> nbm=32,nbn=48. Region/XCD = 32 rows x 6 cols, bm-fastest.
__global__ __launch_bounds__(256) void g1_qkv128(GemmP p) {
  const int x = blockIdx.x & 7, i = blockIdx.x >> 3;  // i in [0,192)
  const int bm = i & 31;
  const int bn = x * 6 + (i >> 5);
  gemm128_body<0>(p, bm << 7, bn << 7, 0, p.K >> 5);
}
// G2: M=4096,N=2048 -> nbm=32,nbn=16. Region/XCD = 8x8.
__global__ __launch_bounds__(256) void g2_proj128(GemmP p) {
  const int x = blockIdx.x & 7, i = blockIdx.x >> 3;  // i in [0,64)
  const int bm = (x >> 1) * 8 + (i >> 3);
  const int bn = (x & 1) * 8 + (i & 7);
  gemm128_body<1>(p, bm << 7, bn << 7, 0, p.K >> 5);
}
// G4 split-K2 (reverted from K4: K4 raised FETCH + drain overhead, R7 regression)
__global__ __launch_bounds__(256) void g4_splitk(GemmP p) {
  const int x = blockIdx.x & 7, i = blockIdx.x >> 3;  // i in [0,128)
  const int ks = i & 1, j = i >> 1;                   // j in [0,64)
  const int bm = (x >> 1) * 8 + (j >> 3);
  const int bn = (x & 1) * 8 + (j & 7);
  GemmP q = p;
  q.outH = p.outH + (size_t)ks * 4096 * 2048;
  gemm128_body<5>(q, bm << 7, bn << 7, ks << 12, 128);   // K-half = 4096
}

// ---------------------------------------------------------------- 256^2 tile common
DEVI void setup256(const GemmP& p, int m0, int n0,
                   const unsigned short*& gsA0, const unsigned short*& gsA1,
                   const unsigned short*& gsB0, const unsigned short*& gsB1) {
  const int tid = threadIdx.x;
  int r_[2], c_[2];
#pragma unroll
  for (int j = 0; j < 2; ++j) {
    int d = tid * 16 + j * 8192;
    int w = (d & 1023) ^ (((d >> 9) & 1) << 5);   // st_16x32 involution
    r_[j] = ((d >> 10) << 4) + (w >> 6);
    c_[j] = (w & 63) >> 1;
  }
  gsA0 = p.A + (size_t)(m0 + r_[0]) * p.K + c_[0];
  gsA1 = p.A + (size_t)(m0 + r_[1]) * p.K + c_[1];
  gsB0 = p.B + (size_t)(n0 + r_[0]) * p.K + c_[0];
  gsB1 = p.B + (size_t)(n0 + r_[1]) * p.K + c_[1];
}

// epilogue: +bias, fast-GELU -> bf16
DEVI void epi256g(const GemmP& p, f32x4 (&acc)[8][4], int m0, int n0) {
  const int lane = threadIdx.x & 63, wid = threadIdx.x >> 6;
  const int wr = wid >> 2, wc = wid & 3;
  const int lr = lane & 15, lk = lane >> 4;
  const int rbase = m0 + wr * 128 + (lk << 2);
  const int cbase = n0 + wc * 64 + lr;
#pragma unroll
  for (int m = 0; m < 8; ++m) {
#pragma unroll
    for (int n = 0; n < 4; ++n) {
      const int col = cbase + (n << 4);
      const float bb = p.bias[col];
#pragma unroll
      for (int r = 0; r < 4; ++r) {
        const int row = rbase + (m << 4) + r;
        float v = acc[m][n][r] + bb;
        float y = 0.7978845608028654f * (v + 0.044715f * v * v * v);
        float u = __expf(2.f * y);
        float gl = (y > 40.f) ? v : v * (u / (u + 1.f));
        p.outH[(size_t)row * p.N + col] = f2bf(gl);
      }
    }
  }
}

// ---------------------------------------------------------------- 256^2 8-phase (A arm)
DEVI void gemm8p_body(const GemmP& p, unsigned short* lds_raw, int m0, int n0) {
  const int tid = threadIdx.x, lane = tid & 63, wid = tid >> 6;
  const int wr = wid >> 2, wc = wid & 3;
  const int lr = lane & 15, lk = lane >> 4;
  const int fb = (lr * 64 + lk * 16) ^ ((lr & 8) << 2);

  const unsigned short *gsA0, *gsA1, *gsB0, *gsB1;
  setup256(p, m0, n0, gsA0, gsA1, gsB0, gsB1);

#define STAGE_A8(b, kt) do { unsigned short* _d = lds_raw + ((b) << 14);       \
    GLD16(gsA0 + ((size_t)(kt) << 5), _d + (tid << 3));                        \
    GLD16(gsA1 + ((size_t)(kt) << 5), _d + 4096 + (tid << 3)); } while (0)
#define STAGE_B8(b, kt) do { unsigned short* _d = lds_raw + ((b) << 14) + 8192;\
    GLD16(gsB0 + ((size_t)(kt) << 5), _d + (tid << 3));                        \
    GLD16(gsB1 + ((size_t)(kt) << 5), _d + 4096 + (tid << 3)); } while (0)

  f32x4 acc[8][4] = {};
  const int NK = p.K >> 5;

  STAGE_A8(0, 0); STAGE_B8(0, 0);
  STAGE_A8(1, 1); STAGE_B8(1, 1);
  STAGE_A8(2, 2); STAGE_B8(2, 2);
  asm volatile("s_waitcnt vmcnt(8)" ::: "memory");
  __builtin_amdgcn_s_barrier();

  for (int t = 0; t < NK; ++t) {
    const int bi = t & 3;
    const char* tA = (const char*)(lds_raw + (bi << 14));
    const char* tB = (const char*)(lds_raw + (bi << 14) + 8192);
    bf16x8 a_[4], b_[4];
#pragma unroll
    for (int n = 0; n < 4; ++n)
      b_[n] = *(const bf16x8*)(tB + (((wc << 2) + n) << 10) + fb);
#pragma unroll
    for (int m = 0; m < 4; ++m)
      a_[m] = *(const bf16x8*)(tA + (((wr << 3) + m) << 10) + fb);
    if (t + 3 < NK) STAGE_A8((t + 3) & 3, t + 3);
    __builtin_amdgcn_s_barrier();
    asm volatile("s_waitcnt lgkmcnt(0)" ::: "memory");
    __builtin_amdgcn_sched_barrier(0);
    __builtin_amdgcn_s_setprio(1);
#pragma unroll
    for (int m = 0; m < 4; ++m)
#pragma unroll
      for (int n = 0; n < 4; ++n)
        acc[m][n] = __builtin_amdgcn_mfma_f32_16x16x32_bf16(a_[m], b_[n], acc[m][n], 0, 0, 0);
    __builtin_amdgcn_s_setprio(0);
    __builtin_amdgcn_s_barrier();
#pragma unroll
    for (int m = 0; m < 4; ++m)
      a_[m] = *(const bf16x8*)(tA + (((wr << 3) + 4 + m) << 10) + fb);
    if (t + 3 < NK) STAGE_B8((t + 3) & 3, t + 3);
    if (t + 3 < NK)      asm volatile("s_waitcnt vmcnt(8)" ::: "memory");
    else if (t + 2 < NK) asm volatile("s_waitcnt vmcnt(4)" ::: "memory");
    else if (t + 1 < NK) asm volatile("s_waitcnt vmcnt(0)" ::: "memory");
    __builtin_amdgcn_s_barrier();
    asm volatile("s_waitcnt lgkmcnt(0)" ::: "memory");
    __builtin_amdgcn_sched_barrier(0);
    __builtin_amdgcn_s_setprio(1);
#pragma unroll
    for (int m = 0; m < 4; ++m)
#pragma unroll
      for (int n = 0; n < 4; ++n)
        acc[4 + m][n] = __builtin_amdgcn_mfma_f32_16x16x32_bf16(a_[m], b_[n], acc[4 + m][n], 0, 0, 0);
    __builtin_amdgcn_s_setprio(0);
    __builtin_amdgcn_s_barrier();
  }
#undef STAGE_A8
#undef STAGE_B8
  epi256g(p, acc, m0, n0);
}

// ---------------------------------------------------------------- 256^2 2-phase (B arm)
DEVI void gemm2p_body(const GemmP& p, unsigned short* lds_raw, int m0, int n0) {
  const int tid = threadIdx.x, lane = tid & 63, wid = tid >> 6;
  const int wr = wid >> 2, wc = wid & 3;
  const int lr = lane & 15, lk = lane >> 4;
  const int fb = (lr * 64 + lk * 16) ^ ((lr & 8) << 2);

  const unsigned short *gsA0, *gsA1, *gsB0, *gsB1;
  setup256(p, m0, n0, gsA0, gsA1, gsB0, gsB1);

#define STG2(b, kt) do { unsigned short* _d = lds_raw + ((b) << 14);     \
    GLD16(gsA0 + ((size_t)(kt) << 5), _d + (tid << 3));                  \
    GLD16(gsA1 + ((size_t)(kt) << 5), _d + 4096 + (tid << 3));           \
    GLD16(gsB0 + ((size_t)(kt) << 5), _d + 8192 + (tid << 3));           \
    GLD16(gsB1 + ((size_t)(kt) << 5), _d + 12288 + (tid << 3)); } while (0)

  f32x4 acc[8][4] = {};
  const int NK = p.K >> 5;
  STG2(0, 0);
  __syncthreads();
  int cur = 0;
  for (int t = 0; t < NK; ++t) {
    if (t + 1 < NK) STG2(cur ^ 1, t + 1);
    const char* tA = (const char*)(lds_raw + (cur << 14));
    const char* tB = tA + 16384;
    bf16x8 a_[8], b_[4];
#pragma unroll
    for (int n = 0; n < 4; ++n)
      b_[n] = *(const bf16x8*)(tB + (((wc << 2) + n) << 10) + fb);
#pragma unroll
    for (int m = 0; m < 8; ++m)
      a_[m] = *(const bf16x8*)(tA + (((wr << 3) + m) << 10) + fb);
#pragma unroll
    for (int m = 0; m < 8; ++m)
#pragma unroll
      for (int n = 0; n < 4; ++n)
        acc[m][n] = __builtin_amdgcn_mfma_f32_16x16x32_bf16(a_[m], b_[n], acc[m][n], 0, 0, 0);
    __syncthreads();
    cur ^= 1;
  }
#undef STG2
  epi256g(p, acc, m0, n0);
}

// G3a: rows [0,2048), 8-phase. Region 4x8 per XCD
__global__ __launch_bounds__(512, 2) void g3a_fc8p(GemmP p) {
  extern __shared__ unsigned short lds_raw[];
  const int x = blockIdx.x & 7, i = blockIdx.x >> 3;
  const int bm = (x >> 2) * 4 + (i >> 3);
  const int bn = (x & 3) * 8 + (i & 7);
  gemm8p_body(p, lds_raw, bm << 8, bn << 8);
}
// G3b: rows [2048,4096), 2-phase (A/B control)
__global__ __launch_bounds__(512, 2) void g3b_fc2p(GemmP p) {
  extern __shared__ unsigned short lds_raw[];
  const int x = blockIdx.x & 7, i = blockIdx.x >> 3;
  const int bm = (x >> 2) * 4 + (i >> 3);
  const int bn = (x & 3) * 8 + (i & 7);
  gemm2p_body(p, lds_raw, 2048 + (bm << 8), bn << 8);
}

// ---------------------------------------------------------------- attention
// QBLK=128 (8 waves): K/V staging+barriers amortized over 2x waves.
// Q,K from unified qkv [4096][6144]; V^T [32][128][2048]; O bf16 [4096][2048].
__global__ __launch_bounds__(512) void attn_k(const unsigned short* __restrict__ qkv,
                                              const unsigned short* __restrict__ Vt,
                                              unsigned short* __restrict__ O) {
  const int tid = threadIdx.x, lane = tid & 63, wid = tid >> 6;
  const int bid = blockIdx.x;                 // grid = 512
  const int pos = bid >> 3;                   // [0,64)
  const int bh = (bid & 7) * 4 + (pos >> 4);  // 4 (b,h) per XCD
  const int qt = pos & 15;
  const int q0 = qt * 128 + wid * 16;
  const int b = bh >> 4, h = bh & 15;

  __shared__ __align__(16) unsigned short sK[64 * 128];
  __shared__ __align__(16) unsigned short sV[128 * 64];
  __shared__ __align__(16) unsigned short sP[8][16 * 68];   // stride 68: conflict-free

  const unsigned short* Qb = qkv + (size_t)(b * 2048) * 6144 + h * 128;
  const unsigned short* Kb = qkv + (size_t)(b * 2048) * 6144 + 2048 + h * 128;
  const unsigned short* Vb = Vt + ((size_t)bh << 18);

  bf16x8 qf[4];
  {
    const unsigned short* qp = Qb + (size_t)(q0 + (lane & 15)) * 6144 + ((lane >> 4) << 3);
#pragma unroll
    for (int kk = 0; kk < 4; ++kk) qf[kk] = *(const bf16x8*)(qp + kk * 32);
  }

  int koffs[2], voffs[2];
#pragma unroll
  for (int i = 0; i < 2; ++i) {
    const int c = tid + (i << 9);             // [0,1024)
    const int kv = c >> 4, jj = c & 15;
    const int js = (jj & 8) | ((jj ^ kv) & 7);
    koffs[i] = kv * 6144 + (js << 3);
    const int d = c >> 3, j2 = c & 7;
    const int js2 = j2 ^ (d & 7);
    voffs[i] = d * 2048 + (js2 << 3);
  }
  u16x8 kreg[2], vreg[2];
  auto PREF = [&](int kt) {
    const int kv0 = kt << 6;
    const unsigned short* kb = Kb + (size_t)kv0 * 6144;
#pragma unroll
    for (int i = 0; i < 2; ++i) {
      kreg[i] = *(const u16x8*)(kb + koffs[i]);
      vreg[i] = *(const u16x8*)(Vb + kv0 + voffs[i]);
    }
  };

  f32x4 oacc[8] = {};
  float mrun = -3e38f, lrun = 0.f;
  PREF(0);

  for (int kt = 0; kt < 32; ++kt) {
#pragma unroll
    for (int i = 0; i < 2; ++i) {
      const int c8 = (tid + (i << 9)) << 3;
      *(u16x8*)&sK[c8] = kreg[i];
      *(u16x8*)&sV[c8] = vreg[i];
    }
    __syncthreads();
    if (kt + 1 < 32) PREF(kt + 1);

    f32x4 sc[4] = {};
    __builtin_amdgcn_s_setprio(1);
#pragma unroll
    for (int ti = 0; ti < 4; ++ti) {
#pragma unroll
      for (int kk = 0; kk < 4; ++kk) {
        const int row = (ti << 4) + (lane & 15);
        int bo = (row << 8) + (kk << 6) + ((lane >> 4) << 4);
        bo ^= (row & 7) << 4;
        bf16x8 kf = *(const bf16x8*)((const char*)sK + bo);
        sc[ti] = __builtin_amdgcn_mfma_f32_16x16x32_bf16(kf, qf[kk], sc[ti], 0, 0, 0);
      }
    }
    __builtin_amdgcn_s_setprio(0);

    float pv[16];
    float mx = -3e38f;
#pragma unroll
    for (int ti = 0; ti < 4; ++ti)
#pragma unroll
      for (int r = 0; r < 4; ++r) {
        float x = sc[ti][r] * 0.08838834764831845f;
        pv[(ti << 2) + r] = x;
        mx = fmaxf(mx, x);
      }
    mx = fmaxf(mx, __shfl_xor(mx, 16));
    mx = fmaxf(mx, __shfl_xor(mx, 32));

    float corr = 1.f;
    if (!__all(mx - mrun <= 8.f)) {
      const float mnew = fmaxf(mrun, mx);
      corr = __expf(mrun - mnew);
      mrun = mnew;
      float fr[4];
#pragma unroll
      for (int r = 0; r < 4; ++r) fr[r] = __shfl(corr, ((lane >> 4) << 2) + r);
#pragma unroll
      for (int di = 0; di < 8; ++di)
#pragma unroll
        for (int r = 0; r < 4; ++r) oacc[di][r] *= fr[r];
    }
    float psum = 0.f;
#pragma unroll
    for (int i2 = 0; i2 < 16; ++i2) {
      float e = __expf(pv[i2] - mrun);
      pv[i2] = e;
      psum += e;
    }
    psum += __shfl_xor(psum, 16);
    psum += __shfl_xor(psum, 32);
    lrun = lrun * corr + psum;

    unsigned short* prow = &sP[wid][(lane & 15) * 68];
#pragma unroll
    for (int ti = 0; ti < 4; ++ti) {
      u16x4 w4;
      w4.x = f2bf(pv[(ti << 2) + 0]);
      w4.y = f2bf(pv[(ti << 2) + 1]);
      w4.z = f2bf(pv[(ti << 2) + 2]);
      w4.w = f2bf(pv[(ti << 2) + 3]);
      *(u16x4*)&prow[(ti << 4) + ((lane >> 4) << 2)] = w4;
    }

    __builtin_amdgcn_s_setprio(1);
#pragma unroll
    for (int di = 0; di < 8; ++di) {
#pragma unroll
      for (int ks = 0; ks < 2; ++ks) {
        bf16x8 pf = *(const bf16x8*)((const char*)&sP[wid][0] +
                                     (lane & 15) * 136 + (ks << 6) + ((lane >> 4) << 4));
        const int dr = (di << 4) + (lane & 15);
        int bo = (dr << 7) + (ks << 6) + ((lane >> 4) << 4);
        bo ^= (dr & 7) << 4;
        bf16x8 vf = *(const bf16x8*)((const char*)sV + bo);
        oacc[di] = __builtin_amdgcn_mfma_f32_16x16x32_bf16(pf, vf, oacc[di], 0, 0, 0);
      }
    }
    __builtin_amdgcn_s_setprio(0);
    __syncthreads();
  }

  float il[4];
#pragma unroll
  for (int r = 0; r < 4; ++r) il[r] = 1.f / __shfl(lrun, ((lane >> 4) << 2) + r);
  const size_t obase = ((size_t)(b * 2048 + q0)) * 2048 + h * 128;
#pragma unroll
  for (int di = 0; di < 8; ++di)
#pragma unroll
    for (int r = 0; r < 4; ++r) {
      const size_t o = obase + (size_t)(((lane >> 4) << 2) + r) * 2048 + (di << 4) + (lane & 15);
      O[o] = f2bf(oacc[di][r] * il[r]);
    }
}

// ---------------------------------------------------------------- launch

extern "C" void kernel_launch(void* const* d_in, const int* in_sizes, int n_in,
                              void* d_out, int out_size, void* d_ws, size_t ws_size,
                              hipStream_t stream) {
  (void)in_sizes; (void)n_in; (void)out_size; (void)ws_size;
  const float* hidden = (const float*)d_in[0];
  const float* ln1_g = (const float*)d_in[1];
  const float* ln1_b = (const float*)d_in[2];
  const float* w_qkv = (const float*)d_in[3];
  const float* b_qkv = (const float*)d_in[4];
  const float* apv = (const float*)d_in[5];
  const float* apg = (const float*)d_in[6];
  const float* apb = (const float*)d_in[7];
  // d_in[8] emotion_bias: softmax-invariant -> dropped (exact)
  const float* ln2_g = (const float*)d_in[9];
  const float* ln2_b = (const float*)d_in[10];
  const float* w_fc = (const float*)d_in[11];
  const float* b_fc = (const float*)d_in[12];
  const float* mpv = (const float*)d_in[13];
  const float* mpg = (const float*)d_in[14];
  const float* mpb = (const float*)d_in[15];

  char* w = (char*)d_ws;
  const size_t MBs = 1ull << 20;
  // lifetimes: [0,16) xln (LN1->G1) then [0,32) hidden2 (G2->end)
  //            [32,48) vtbuf (vtrans->attn) then [32,96) hbuf (G3->G4red... G4)
  //            [96,144) qkv (G1->attn) then [96,128) wfc_bf (cast->G3) then
  //              [96,128) g4 bf16 partials (G4->reduce); [128,144) xln2 (LN2->G3)
  //            [144,160) attn_out (attn->G2)
  //            [160,184) wqkv_bf (->G1) then [160,192) w2_bf (->G4)
  //            [192,200) wproj_bf; [200+] small scratch
  unsigned short* xln = (unsigned short*)(w + 0);
  float* hidden2 = (float*)(w + 0);
  unsigned short* vtbuf = (unsigned short*)(w + 32 * MBs);
  unsigned short* hbuf = (unsigned short*)(w + 32 * MBs);
  unsigned short* qkv = (unsigned short*)(w + 96 * MBs);
  unsigned short* wfc_bf = (unsigned short*)(w + 96 * MBs);
  unsigned short* partH = (unsigned short*)(w + 96 * MBs);
  unsigned short* xln2 = (unsigned short*)(w + 128 * MBs);
  unsigned short* attn_out = (unsigned short*)(w + 144 * MBs);
  unsigned short* wqkv_bf = (unsigned short*)(w + 160 * MBs);
  unsigned short* w2_bf = (unsigned short*)(w + 160 * MBs);
  unsigned short* wproj_bf = (unsigned short*)(w + 192 * MBs);
  float* s_attn = (float*)(w + 200 * MBs);
  float* s_mlp = (float*)(w + 200 * MBs + 32768);
  float* part_attn = (float*)(w + 201 * MBs);
  float* part_mlp = (float*)(w + 202 * MBs);

  hipFuncSetAttribute((const void*)g3a_fc8p, hipFuncAttributeMaxDynamicSharedMemorySize, 131072);
  hipFuncSetAttribute((const void*)g3b_fc2p, hipFuncAttributeMaxDynamicSharedMemorySize, 65536);

  // weight prep
  cast_k<<<2048, 256, 0, stream>>>(w_qkv, wqkv_bf, (6144 * 2048) / 4);
  colnorm1_k<<<dim3(4, 32), 256, 0, stream>>>(apv, part_attn, 2048);
  colnorm2_k<<<8, 256, 0, stream>>>(part_attn, apg, s_attn, 2048, 32);
  scale_cast_k<<<2048, 256, 0, stream>>>(apv, s_attn, wproj_bf, 2048, (2048 * 2048) / 4);
  colnorm1_k<<<dim3(16, 32), 256, 0, stream>>>(mpv, part_mlp, 8192);
  colnorm2_k<<<32, 256, 0, stream>>>(part_mlp, mpg, s_mlp, 8192, 32);

  // LN1 -> xln (bf16)
  ln_k<<<4096, 256, 0, stream>>>(hidden, ln1_g, ln1_b, xln);

  // GEMM1 (128^2, unified-qkv epilogue): qkv = xln @ w_qkv^T + b
  GemmP p1 = {xln, wqkv_bf, b_qkv, nullptr, nullptr, qkv, 4096, 6144, 2048};
  g1_qkv128<<<1536, 256, 0, stream>>>(p1);

  // V slice of qkv -> V^T
  vtrans_k<<<1024, 256, 0, stream>>>(qkv, vtbuf);

  // attention (QBLK=128, 8 waves) -> attn_out
  attn_k<<<512, 512, 0, stream>>>(qkv, vtbuf, attn_out);

  // weight casts for MLP
  cast_k<<<2048, 256, 0, stream>>>(w_fc, wfc_bf, (8192 * 2048) / 4);
  scale_cast_k<<<4096, 256, 0, stream>>>(mpv, s_mlp, w2_bf, 8192, (2048 * 8192) / 4);

  // GEMM2 (128^2): hidden2 = attn_out @ w_proj^T + b + hidden
  GemmP p2 = {attn_out, wproj_bf, apb, hidden, hidden2, nullptr, 4096, 2048, 2048};
  g2_proj128<<<512, 256, 0, stream>>>(p2);

  // LN2 -> xln2
  ln_k<<<4096, 256, 0, stream>>>(hidden2, ln2_g, ln2_b, xln2);

  // GEMM3 A/B experiment: rows 0-2047 8-phase, rows 2048-4095 2-phase
  GemmP p3 = {xln2, wfc_bf, b_fc, nullptr, nullptr, hbuf, 4096, 8192, 2048};
  g3a_fc8p<<<256, 512, 131072, stream>>>(p3);
  g3b_fc2p<<<256, 512, 65536, stream>>>(p3);

  // GEMM4 split-K2 (1024 blocks, bf16 partials) -> fused reduce
  GemmP p4 = {hbuf, w2_bf, mpb, nullptr, nullptr, partH, 4096, 2048, 8192};
  g4_splitk<<<1024, 256, 0, stream>>>(p4);
  g4red_k<<<2048, 256, 0, stream>>>(partH, mpb, hidden2, (float*)d_out,
                                    (4096 * 2048) / 4);
}

// Round 9
// 862.510 us; speedup vs baseline: 1.0413x; 1.0382x over previous
//
#include <hip/hip_runtime.h>
#include <hip/hip_bf16.h>

#define DEVI __device__ __forceinline__

typedef __attribute__((ext_vector_type(8))) __bf16 bf16x8;
typedef __attribute__((ext_vector_type(4))) float f32x4;
typedef __attribute__((ext_vector_type(4))) unsigned short u16x4;
typedef __attribute__((ext_vector_type(8))) unsigned short u16x8;

DEVI unsigned short f2bf(float f) {
  unsigned int u = __float_as_uint(f);
  u += 0x7FFFu + ((u >> 16) & 1u);   // RNE
  return (unsigned short)(u >> 16);
}
DEVI float bf2f(unsigned short u) {
  return __uint_as_float(((unsigned int)u) << 16);
}

#define GLD16(g, l) __builtin_amdgcn_global_load_lds(                      \
    (const __attribute__((address_space(1))) void*)(g),                    \
    (__attribute__((address_space(3))) void*)(l), 16, 0, 0)

// ---------------------------------------------------------------- helpers

__global__ __launch_bounds__(256) void cast_k(const float* __restrict__ in,
                                              unsigned short* __restrict__ out,
                                              int n4) {
  for (int i = blockIdx.x * 256 + threadIdx.x; i < n4; i += gridDim.x * 256) {
    f32x4 v = ((const f32x4*)in)[i];
    u16x4 o;
    o.x = f2bf(v.x); o.y = f2bf(v.y); o.z = f2bf(v.z); o.w = f2bf(v.w);
    ((u16x4*)out)[i] = o;
  }
}

// colnorm phase 1: partial column sumsq over a 64-row x 512-col tile.
__global__ __launch_bounds__(256) void colnorm1_k(const float* __restrict__ v,
                                                  float* __restrict__ part,
                                                  int cols) {
  const int tid = threadIdx.x;
  const int g = tid & 127;
  const int s = tid >> 7;
  const int c0 = blockIdx.x * 512;
  const int r0 = blockIdx.y * 64 + s * 32;
  const float* base = v + (size_t)r0 * cols + c0 + g * 4;
  f32x4 acc = {};
#pragma unroll 4
  for (int i = 0; i < 32; ++i) {
    f32x4 x = *(const f32x4*)(base + (size_t)i * cols);
    acc.x += x.x * x.x; acc.y += x.y * x.y;
    acc.z += x.z * x.z; acc.w += x.w * x.w;
  }
  __shared__ f32x4 red[256];
  red[tid] = acc;
  __syncthreads();
  if (s == 0) {
    f32x4 a = red[tid], b = red[tid + 128];
    f32x4 o;
    o.x = a.x + b.x; o.y = a.y + b.y; o.z = a.z + b.z; o.w = a.w + b.w;
    *(f32x4*)(part + (size_t)blockIdx.y * cols + c0 + g * 4) = o;
  }
}

// colnorm phase 2: s[c] = g[c] * rsqrt(sum_rc part[rc][c])
__global__ __launch_bounds__(256) void colnorm2_k(const float* __restrict__ part,
                                                  const float* __restrict__ g,
                                                  float* __restrict__ s,
                                                  int cols, int nrc) {
  const int c = blockIdx.x * 256 + threadIdx.x;
  float acc = 0.f;
  for (int i = 0; i < nrc; ++i) acc += part[(size_t)i * cols + c];
  s[c] = g[c] * rsqrtf(acc);
}

__global__ __launch_bounds__(256) void scale_cast_k(const float* __restrict__ in,
                                                    const float* __restrict__ s,
                                                    unsigned short* __restrict__ out,
                                                    int cols, int n4) {
  const int cmask4 = (cols >> 2) - 1;
  for (int i = blockIdx.x * 256 + threadIdx.x; i < n4; i += gridDim.x * 256) {
    f32x4 v = ((const f32x4*)in)[i];
    f32x4 sv = ((const f32x4*)s)[i & cmask4];
    u16x4 o;
    o.x = f2bf(v.x * sv.x); o.y = f2bf(v.y * sv.y);
    o.z = f2bf(v.z * sv.z); o.w = f2bf(v.w * sv.w);
    ((u16x4*)out)[i] = o;
  }
}

// LayerNorm: one block per row of 2048 fp32, out bf16
__global__ __launch_bounds__(256) void ln_k(const float* __restrict__ x,
                                            const float* __restrict__ g,
                                            const float* __restrict__ b,
                                            unsigned short* __restrict__ out) {
  const int tid = threadIdx.x, lane = tid & 63, wid = tid >> 6;
  const int row = blockIdx.x;
  const float* xr = x + (size_t)row * 2048;
  f32x4 a0 = ((const f32x4*)xr)[tid];
  f32x4 a1 = ((const f32x4*)xr)[tid + 256];
  float s = a0.x + a0.y + a0.z + a0.w + a1.x + a1.y + a1.z + a1.w;
  float ss = a0.x * a0.x + a0.y * a0.y + a0.z * a0.z + a0.w * a0.w +
             a1.x * a1.x + a1.y * a1.y + a1.z * a1.z + a1.w * a1.w;
#pragma unroll
  for (int m = 1; m < 64; m <<= 1) {
    s += __shfl_xor(s, m);
    ss += __shfl_xor(ss, m);
  }
  __shared__ float red[8];
  if (lane == 0) { red[wid] = s; red[4 + wid] = ss; }
  __syncthreads();
  s = red[0] + red[1] + red[2] + red[3];
  ss = red[4] + red[5] + red[6] + red[7];
  const float mu = s * (1.f / 2048.f);
  const float var = ss * (1.f / 2048.f) - mu * mu;
  const float rs = rsqrtf(var + 1e-5f);
  f32x4 g0 = ((const f32x4*)g)[tid], g1 = ((const f32x4*)g)[tid + 256];
  f32x4 b0 = ((const f32x4*)b)[tid], b1 = ((const f32x4*)b)[tid + 256];
  u16x4 o0, o1;
  o0.x = f2bf((a0.x - mu) * rs * g0.x + b0.x);
  o0.y = f2bf((a0.y - mu) * rs * g0.y + b0.y);
  o0.z = f2bf((a0.z - mu) * rs * g0.z + b0.z);
  o0.w = f2bf((a0.w - mu) * rs * g0.w + b0.w);
  o1.x = f2bf((a1.x - mu) * rs * g1.x + b1.x);
  o1.y = f2bf((a1.y - mu) * rs * g1.y + b1.y);
  o1.z = f2bf((a1.z - mu) * rs * g1.z + b1.z);
  o1.w = f2bf((a1.w - mu) * rs * g1.w + b1.w);
  unsigned short* orow = out + (size_t)row * 2048;
  *(u16x4*)(orow + 4 * tid) = o0;
  *(u16x4*)(orow + 1024 + 4 * tid) = o1;
}

// V transpose: V slice of qkv [4096][6144] -> vt [32][128][2048]
__global__ __launch_bounds__(256) void vtrans_k(const unsigned short* __restrict__ qkv,
                                                unsigned short* __restrict__ vt) {
  __shared__ unsigned short t[64][134];
  const int tid = threadIdx.x;
  const int bh = blockIdx.x >> 5, st = blockIdx.x & 31;
  const int b = bh >> 4, h = bh & 15;
  const unsigned short* vb = qkv + (size_t)(b * 2048 + st * 64) * 6144 + 4096 + h * 128;
#pragma unroll
  for (int i = 0; i < 4; ++i) {
    int f = tid + (i << 8);
    int row = f >> 4, c8 = f & 15;
    u16x8 x = *(const u16x8*)(vb + (size_t)row * 6144 + c8 * 8);
#pragma unroll
    for (int j = 0; j < 4; ++j) {
      unsigned int pk = ((unsigned int)x[2 * j + 1] << 16) | x[2 * j];
      *(unsigned int*)&t[row][c8 * 8 + 2 * j] = pk;
    }
  }
  __syncthreads();
  const int lane = tid & 63, wid = tid >> 6;
  unsigned short* ob = vt + ((size_t)bh << 18) + (st << 6);
#pragma unroll
  for (int j = 0; j < 32; ++j) {
    int d = (wid << 5) + j;
    ob[((size_t)d << 11) + lane] = t[lane][d];
  }
}

// split-K4 reduce: out = sum(bf16 parts 0..3) + bias + res (fp32)
__global__ __launch_bounds__(256) void g4red_k(const unsigned short* __restrict__ parts,
                                               const float* __restrict__ bias,
                                               const float* __restrict__ res,
                                               float* __restrict__ out, int n4) {
  const size_t PS = (size_t)4096 * 2048;
  for (int i = blockIdx.x * 256 + threadIdx.x; i < n4; i += gridDim.x * 256) {
    u16x4 a = ((const u16x4*)(parts))[i];
    u16x4 b = ((const u16x4*)(parts + PS))[i];
    u16x4 c = ((const u16x4*)(parts + 2 * PS))[i];
    u16x4 d = ((const u16x4*)(parts + 3 * PS))[i];
    f32x4 r = ((const f32x4*)res)[i];
    f32x4 bb = ((const f32x4*)bias)[i & 511];
    f32x4 o;
    o.x = bf2f(a.x) + bf2f(b.x) + bf2f(c.x) + bf2f(d.x) + r.x + bb.x;
    o.y = bf2f(a.y) + bf2f(b.y) + bf2f(c.y) + bf2f(d.y) + r.y + bb.y;
    o.z = bf2f(a.z) + bf2f(b.z) + bf2f(c.z) + bf2f(d.z) + r.z + bb.z;
    o.w = bf2f(a.w) + bf2f(b.w) + bf2f(c.w) + bf2f(d.w) + r.w + bb.w;
    ((f32x4*)out)[i] = o;
  }
}

// ---------------------------------------------------------------- GEMM params
struct GemmP {
  const unsigned short* A;
  const unsigned short* B;
  const float* bias;
  const float* res;
  float* outF;
  unsigned short* outH;
  int M, N, K;
};

// ---------------------------------------------------------------- 128^2 GEMM (2-phase)
// EPI: 1 = +bias+res -> fp32
DEVI void gemm128_body(const GemmP& p, int m0, int n0, int k0, int nk) {
  const int tid = threadIdx.x, lane = tid & 63, wid = tid >> 6;
  const int K = p.K;
  const int wr = wid >> 1, wc = wid & 1;

  __shared__ __align__(16) unsigned short sA[2][4096];
  __shared__ __align__(16) unsigned short sB[2][4096];

  const int c0 = tid, c1 = tid + 256;
  const unsigned short* gA0 = p.A + (size_t)(m0 + (c0 >> 2)) * K + k0 + ((c0 & 3) << 3);
  const unsigned short* gA1 = p.A + (size_t)(m0 + (c1 >> 2)) * K + k0 + ((c1 & 3) << 3);
  const unsigned short* gB0 = p.B + (size_t)(n0 + (c0 >> 2)) * K + k0 + ((c0 & 3) << 3);
  const unsigned short* gB1 = p.B + (size_t)(n0 + (c1 >> 2)) * K + k0 + ((c1 & 3) << 3);
  const int l0 = wid << 9, l1 = (wid << 9) + 2048;

  f32x4 acc[4][4] = {};
  const int arow = (wr << 6) + (lane & 15);
  const int brow = (wc << 6) + (lane & 15);
  const int koff = (lane >> 4) << 3;

#define STAGE128(bufi, t) do { int ko = (t) << 5;       \
    GLD16(gA0 + ko, &sA[bufi][l0]);                     \
    GLD16(gA1 + ko, &sA[bufi][l1]);                     \
    GLD16(gB0 + ko, &sB[bufi][l0]);                     \
    GLD16(gB1 + ko, &sB[bufi][l1]); } while (0)

  STAGE128(0, 0);
  __syncthreads();
  int cur = 0;
  for (int t = 0; t < nk; ++t) {
    if (t + 1 < nk) STAGE128(cur ^ 1, t + 1);
    bf16x8 af[4], bfr[4];
#pragma unroll
    for (int i = 0; i < 4; ++i)
      af[i] = *(const bf16x8*)&sA[cur][(arow + (i << 4)) * 32 + koff];
#pragma unroll
    for (int i = 0; i < 4; ++i)
      bfr[i] = *(const bf16x8*)&sB[cur][(brow + (i << 4)) * 32 + koff];
#pragma unroll
    for (int i = 0; i < 4; ++i)
#pragma unroll
      for (int j = 0; j < 4; ++j)
        acc[i][j] = __builtin_amdgcn_mfma_f32_16x16x32_bf16(af[i], bfr[j], acc[i][j], 0, 0, 0);
    __syncthreads();
    cur ^= 1;
  }
#undef STAGE128

  const int rbase = m0 + (wr << 6) + ((lane >> 4) << 2);
  const int cbase = n0 + (wc << 6) + (lane & 15);
#pragma unroll
  for (int mi = 0; mi < 4; ++mi) {
#pragma unroll
    for (int ni = 0; ni < 4; ++ni) {
      const int col = cbase + (ni << 4);
#pragma unroll
      for (int r = 0; r < 4; ++r) {
        const int row = rbase + (mi << 4) + r;
        const size_t o = (size_t)row * p.N + col;
        p.outF[o] = acc[mi][ni][r] + p.bias[col] + p.res[o];
      }
    }
  }
}

// G2: M=4096,N=2048 -> nbm=32,nbn=16. Region/XCD = 8x8.
__global__ __launch_bounds__(256) void g2_proj128(GemmP p) {
  const int x = blockIdx.x & 7, i = blockIdx.x >> 3;  // i in [0,64)
  const int bm = (x >> 1) * 8 + (i >> 3);
  const int bn = (x & 1) * 8 + (i & 7);
  gemm128_body(p, bm << 7, bn << 7, 0, p.K >> 5);
}

// ---------------------------------------------------------------- 256^2 tile common
DEVI void setup256(const GemmP& p, int m0, int n0, int k0,
                   const unsigned short*& gsA0, const unsigned short*& gsA1,
                   const unsigned short*& gsB0, const unsigned short*& gsB1) {
  const int tid = threadIdx.x;
  int r_[2], c_[2];
#pragma unroll
  for (int j = 0; j < 2; ++j) {
    int d = tid * 16 + j * 8192;
    int w = (d & 1023) ^ (((d >> 9) & 1) << 5);   // st_16x32 involution
    r_[j] = ((d >> 10) << 4) + (w >> 6);
    c_[j] = (w & 63) >> 1;
  }
  gsA0 = p.A + (size_t)(m0 + r_[0]) * p.K + k0 + c_[0];
  gsA1 = p.A + (size_t)(m0 + r_[1]) * p.K + k0 + c_[1];
  gsB0 = p.B + (size_t)(n0 + r_[0]) * p.K + k0 + c_[0];
  gsB1 = p.B + (size_t)(n0 + r_[1]) * p.K + k0 + c_[1];
}

// epilogue: EPI 0 = +bias -> bf16   2 = +bias fast-GELU -> bf16   5 = raw -> bf16
template <int EPI>
DEVI void epi256(const GemmP& p, f32x4 (&acc)[8][4], int m0, int n0,
                 unsigned short* outH) {
  const int lane = threadIdx.x & 63, wid = threadIdx.x >> 6;
  const int wr = wid >> 2, wc = wid & 3;
  const int lr = lane & 15, lk = lane >> 4;
  const int rbase = m0 + wr * 128 + (lk << 2);
  const int cbase = n0 + wc * 64 + lr;
#pragma unroll
  for (int m = 0; m < 8; ++m) {
#pragma unroll
    for (int n = 0; n < 4; ++n) {
      const int col = cbase + (n << 4);
      const float bb = (EPI == 5) ? 0.f : p.bias[col];
#pragma unroll
      for (int r = 0; r < 4; ++r) {
        const int row = rbase + (m << 4) + r;
        float v = acc[m][n][r] + bb;
        if constexpr (EPI == 2) {
          float y = 0.7978845608028654f * (v + 0.044715f * v * v * v);
          float u = __expf(2.f * y);
          v = (y > 40.f) ? v : v * (u / (u + 1.f));
        }
        outH[(size_t)row * p.N + col] = f2bf(v);
      }
    }
  }
}

// ---------------------------------------------------------------- 256^2 8-phase (A arm)
DEVI void gemm8p_body(const GemmP& p, unsigned short* lds_raw, int m0, int n0) {
  const int tid = threadIdx.x, lane = tid & 63, wid = tid >> 6;
  const int wr = wid >> 2, wc = wid & 3;
  const int lr = lane & 15, lk = lane >> 4;
  const int fb = (lr * 64 + lk * 16) ^ ((lr & 8) << 2);

  const unsigned short *gsA0, *gsA1, *gsB0, *gsB1;
  setup256(p, m0, n0, 0, gsA0, gsA1, gsB0, gsB1);

#define STAGE_A8(b, kt) do { unsigned short* _d = lds_raw + ((b) << 14);       \
    GLD16(gsA0 + ((size_t)(kt) << 5), _d + (tid << 3));                        \
    GLD16(gsA1 + ((size_t)(kt) << 5), _d + 4096 + (tid << 3)); } while (0)
#define STAGE_B8(b, kt) do { unsigned short* _d = lds_raw + ((b) << 14) + 8192;\
    GLD16(gsB0 + ((size_t)(kt) << 5), _d + (tid << 3));                        \
    GLD16(gsB1 + ((size_t)(kt) << 5), _d + 4096 + (tid << 3)); } while (0)

  f32x4 acc[8][4] = {};
  const int NK = p.K >> 5;

  STAGE_A8(0, 0); STAGE_B8(0, 0);
  STAGE_A8(1, 1); STAGE_B8(1, 1);
  STAGE_A8(2, 2); STAGE_B8(2, 2);
  asm volatile("s_waitcnt vmcnt(8)" ::: "memory");
  __builtin_amdgcn_s_barrier();

  for (int t = 0; t < NK; ++t) {
    const int bi = t & 3;
    const char* tA = (const char*)(lds_raw + (bi << 14));
    const char* tB = (const char*)(lds_raw + (bi << 14) + 8192);
    bf16x8 a_[4], b_[4];
#pragma unroll
    for (int n = 0; n < 4; ++n)
      b_[n] = *(const bf16x8*)(tB + (((wc << 2) + n) << 10) + fb);
#pragma unroll
    for (int m = 0; m < 4; ++m)
      a_[m] = *(const bf16x8*)(tA + (((wr << 3) + m) << 10) + fb);
    if (t + 3 < NK) STAGE_A8((t + 3) & 3, t + 3);
    __builtin_amdgcn_s_barrier();
    asm volatile("s_waitcnt lgkmcnt(0)" ::: "memory");
    __builtin_amdgcn_sched_barrier(0);
    __builtin_amdgcn_s_setprio(1);
#pragma unroll
    for (int m = 0; m < 4; ++m)
#pragma unroll
      for (int n = 0; n < 4; ++n)
        acc[m][n] = __builtin_amdgcn_mfma_f32_16x16x32_bf16(a_[m], b_[n], acc[m][n], 0, 0, 0);
    __builtin_amdgcn_s_setprio(0);
    __builtin_amdgcn_s_barrier();
#pragma unroll
    for (int m = 0; m < 4; ++m)
      a_[m] = *(const bf16x8*)(tA + (((wr << 3) + 4 + m) << 10) + fb);
    if (t + 3 < NK) STAGE_B8((t + 3) & 3, t + 3);
    if (t + 3 < NK)      asm volatile("s_waitcnt vmcnt(8)" ::: "memory");
    else if (t + 2 < NK) asm volatile("s_waitcnt vmcnt(4)" ::: "memory");
    else if (t + 1 < NK) asm volatile("s_waitcnt vmcnt(0)" ::: "memory");
    __builtin_amdgcn_s_barrier();
    asm volatile("s_waitcnt lgkmcnt(0)" ::: "memory");
    __builtin_amdgcn_sched_barrier(0);
    __builtin_amdgcn_s_setprio(1);
#pragma unroll
    for (int m = 0; m < 4; ++m)
#pragma unroll
      for (int n = 0; n < 4; ++n)
        acc[4 + m][n] = __builtin_amdgcn_mfma_f32_16x16x32_bf16(a_[m], b_[n], acc[4 + m][n], 0, 0, 0);
    __builtin_amdgcn_s_setprio(0);
    __builtin_amdgcn_s_barrier();
  }
#undef STAGE_A8
#undef STAGE_B8
  epi256<2>(p, acc, m0, n0, p.outH);
}

// ---------------------------------------------------------------- 256^2 2-phase
template <int EPI>
DEVI void gemm2p_body(const GemmP& p, unsigned short* lds_raw, int m0, int n0,
                      int k0, int nk, unsigned short* outH) {
  const int tid = threadIdx.x, lane = tid & 63, wid = tid >> 6;
  const int wr = wid >> 2, wc = wid & 3;
  const int lr = lane & 15, lk = lane >> 4;
  const int fb = (lr * 64 + lk * 16) ^ ((lr & 8) << 2);

  const unsigned short *gsA0, *gsA1, *gsB0, *gsB1;
  setup256(p, m0, n0, k0, gsA0, gsA1, gsB0, gsB1);

#define STG2(b, kt) do { unsigned short* _d = lds_raw + ((b) << 14);     \
    GLD16(gsA0 + ((size_t)(kt) << 5), _d + (tid << 3));                  \
    GLD16(gsA1 + ((size_t)(kt) << 5), _d + 4096 + (tid << 3));           \
    GLD16(gsB0 + ((size_t)(kt) << 5), _d + 8192 + (tid << 3));           \
    GLD16(gsB1 + ((size_t)(kt) << 5), _d + 12288 + (tid << 3)); } while (0)

  f32x4 acc[8][4] = {};
  STG2(0, 0);
  __syncthreads();
  int cur = 0;
  for (int t = 0; t < nk; ++t) {
    if (t + 1 < nk) STG2(cur ^ 1, t + 1);
    const char* tA = (const char*)(lds_raw + (cur << 14));
    const char* tB = tA + 16384;
    bf16x8 a_[8], b_[4];
#pragma unroll
    for (int n = 0; n < 4; ++n)
      b_[n] = *(const bf16x8*)(tB + (((wc << 2) + n) << 10) + fb);
#pragma unroll
    for (int m = 0; m < 8; ++m)
      a_[m] = *(const bf16x8*)(tA + (((wr << 3) + m) << 10) + fb);
#pragma unroll
    for (int m = 0; m < 8; ++m)
#pragma unroll
      for (int n = 0; n < 4; ++n)
        acc[m][n] = __builtin_amdgcn_mfma_f32_16x16x32_bf16(a_[m], b_[n], acc[m][n], 0, 0, 0);
    __syncthreads();
    cur ^= 1;
  }
#undef STG2
  epi256<EPI>(p, acc, m0, n0, outH);
}

// G1 (256^2 2-phase): M=4096,N=6144 -> nbm=16,nbn=24; region 8x6 per XCD.
// 384 blocks @ 64KB LDS -> all co-resident (2/CU capacity).
__global__ __launch_bounds__(512, 2) void g1_qkv256(GemmP p) {
  extern __shared__ unsigned short lds_raw[];
  const int x = blockIdx.x & 7, i = blockIdx.x >> 3;   // i in [0,48)
  const int bm = (x & 1) * 8 + (i & 7);
  const int bn = (x >> 1) * 6 + (i >> 3);
  gemm2p_body<0>(p, lds_raw, bm << 8, bn << 8, 0, p.K >> 5, p.outH);
}
// G3a: rows [0,2048), 8-phase (A/B arm). Region 4x8 per XCD
__global__ __launch_bounds__(512, 2) void g3a_fc8p(GemmP p) {
  extern __shared__ unsigned short lds_raw[];
  const int x = blockIdx.x & 7, i = blockIdx.x >> 3;
  const int bm = (x >> 2) * 4 + (i >> 3);
  const int bn = (x & 3) * 8 + (i & 7);
  gemm8p_body(p, lds_raw, bm << 8, bn << 8);
}
// G3b: rows [2048,4096), 2-phase (A/B control)
__global__ __launch_bounds__(512, 2) void g3b_fc2p(GemmP p) {
  extern __shared__ unsigned short lds_raw[];
  const int x = blockIdx.x & 7, i = blockIdx.x >> 3;
  const int bm = (x >> 2) * 4 + (i >> 3);
  const int bn = (x & 3) * 8 + (i & 7);
  gemm2p_body<2>(p, lds_raw, 2048 + (bm << 8), bn << 8, 0, p.K >> 5, p.outH);
}
// G4 (256^2 2-phase, split-K4): nbm=16,nbn=8, ks in [0,4). 512 blocks = 2/CU.
// XCD map: ks = x&3 (2 XCDs per K-quarter -> 16MB hot-set/XCD), m-band = x>>2.
__global__ __launch_bounds__(512, 2) void g4_splitk256(GemmP p) {
  extern __shared__ unsigned short lds_raw[];
  const int x = blockIdx.x & 7, i = blockIdx.x >> 3;   // i in [0,64)
  const int ks = x & 3;
  const int bm = (x >> 2) * 8 + (i >> 3);
  const int bn = i & 7;
  unsigned short* outH = p.outH + (size_t)ks * 4096 * 2048;
  gemm2p_body<5>(p, lds_raw, bm << 8, bn << 8, ks << 11, 64, outH);
}

// ---------------------------------------------------------------- attention
// QBLK=128 (8 waves). Q,K from unified qkv [4096][6144]; V^T [32][128][2048].
__global__ __launch_bounds__(512) void attn_k(const unsigned short* __restrict__ qkv,
                                              const unsigned short* __restrict__ Vt,
                                              unsigned short* __restrict__ O) {
  const int tid = threadIdx.x, lane = tid & 63, wid = tid >> 6;
  const int bid = blockIdx.x;                 // grid = 512
  const int pos = bid >> 3;                   // [0,64)
  const int bh = (bid & 7) * 4 + (pos >> 4);
  const int qt = pos & 15;
  const int q0 = qt * 128 + wid * 16;
  const int b = bh >> 4, h = bh & 15;

  __shared__ __align__(16) unsigned short sK[64 * 128];
  __shared__ __align__(16) unsigned short sV[128 * 64];
  __shared__ __align__(16) unsigned short sP[8][16 * 68];

  const unsigned short* Qb = qkv + (size_t)(b * 2048) * 6144 + h * 128;
  const unsigned short* Kb = qkv + (size_t)(b * 2048) * 6144 + 2048 + h * 128;
  const unsigned short* Vb = Vt + ((size_t)bh << 18);

  bf16x8 qf[4];
  {
    const unsigned short* qp = Qb + (size_t)(q0 + (lane & 15)) * 6144 + ((lane >> 4) << 3);
#pragma unroll
    for (int kk = 0; kk < 4; ++kk) qf[kk] = *(const bf16x8*)(qp + kk * 32);
  }

  int koffs[2], voffs[2];
#pragma unroll
  for (int i = 0; i < 2; ++i) {
    const int c = tid + (i << 9);
    const int kv = c >> 4, jj = c & 15;
    const int js = (jj & 8) | ((jj ^ kv) & 7);
    koffs[i] = kv * 6144 + (js << 3);
    const int d = c >> 3, j2 = c & 7;
    const int js2 = j2 ^ (d & 7);
    voffs[i] = d * 2048 + (js2 << 3);
  }
  u16x8 kreg[2], vreg[2];
  auto PREF = [&](int kt) {
    const int kv0 = kt << 6;
    const unsigned short* kb = Kb + (size_t)kv0 * 6144;
#pragma unroll
    for (int i = 0; i < 2; ++i) {
      kreg[i] = *(const u16x8*)(kb + koffs[i]);
      vreg[i] = *(const u16x8*)(Vb + kv0 + voffs[i]);
    }
  };

  f32x4 oacc[8] = {};
  float mrun = -3e38f, lrun = 0.f;
  PREF(0);

  for (int kt = 0; kt < 32; ++kt) {
#pragma unroll
    for (int i = 0; i < 2; ++i) {
      const int c8 = (tid + (i << 9)) << 3;
      *(u16x8*)&sK[c8] = kreg[i];
      *(u16x8*)&sV[c8] = vreg[i];
    }
    __syncthreads();
    if (kt + 1 < 32) PREF(kt + 1);

    f32x4 sc[4] = {};
    __builtin_amdgcn_s_setprio(1);
#pragma unroll
    for (int ti = 0; ti < 4; ++ti) {
#pragma unroll
      for (int kk = 0; kk < 4; ++kk) {
        const int row = (ti << 4) + (lane & 15);
        int bo = (row << 8) + (kk << 6) + ((lane >> 4) << 4);
        bo ^= (row & 7) << 4;
        bf16x8 kf = *(const bf16x8*)((const char*)sK + bo);
        sc[ti] = __builtin_amdgcn_mfma_f32_16x16x32_bf16(kf, qf[kk], sc[ti], 0, 0, 0);
      }
    }
    __builtin_amdgcn_s_setprio(0);

    float pv[16];
    float mx = -3e38f;
#pragma unroll
    for (int ti = 0; ti < 4; ++ti)
#pragma unroll
      for (int r = 0; r < 4; ++r) {
        float x = sc[ti][r] * 0.08838834764831845f;
        pv[(ti << 2) + r] = x;
        mx = fmaxf(mx, x);
      }
    mx = fmaxf(mx, __shfl_xor(mx, 16));
    mx = fmaxf(mx, __shfl_xor(mx, 32));

    float corr = 1.f;
    if (!__all(mx - mrun <= 8.f)) {
      const float mnew = fmaxf(mrun, mx);
      corr = __expf(mrun - mnew);
      mrun = mnew;
      float fr[4];
#pragma unroll
      for (int r = 0; r < 4; ++r) fr[r] = __shfl(corr, ((lane >> 4) << 2) + r);
#pragma unroll
      for (int di = 0; di < 8; ++di)
#pragma unroll
        for (int r = 0; r < 4; ++r) oacc[di][r] *= fr[r];
    }
    float psum = 0.f;
#pragma unroll
    for (int i2 = 0; i2 < 16; ++i2) {
      float e = __expf(pv[i2] - mrun);
      pv[i2] = e;
      psum += e;
    }
    psum += __shfl_xor(psum, 16);
    psum += __shfl_xor(psum, 32);
    lrun = lrun * corr + psum;

    unsigned short* prow = &sP[wid][(lane & 15) * 68];
#pragma unroll
    for (int ti = 0; ti < 4; ++ti) {
      u16x4 w4;
      w4.x = f2bf(pv[(ti << 2) + 0]);
      w4.y = f2bf(pv[(ti << 2) + 1]);
      w4.z = f2bf(pv[(ti << 2) + 2]);
      w4.w = f2bf(pv[(ti << 2) + 3]);
      *(u16x4*)&prow[(ti << 4) + ((lane >> 4) << 2)] = w4;
    }

    __builtin_amdgcn_s_setprio(1);
#pragma unroll
    for (int di = 0; di < 8; ++di) {
#pragma unroll
      for (int ks = 0; ks < 2; ++ks) {
        bf16x8 pf = *(const bf16x8*)((const char*)&sP[wid][0] +
                                     (lane & 15) * 136 + (ks << 6) + ((lane >> 4) << 4));
        const int dr = (di << 4) + (lane & 15);
        int bo = (dr << 7) + (ks << 6) + ((lane >> 4) << 4);
        bo ^= (dr & 7) << 4;
        bf16x8 vf = *(const bf16x8*)((const char*)sV + bo);
        oacc[di] = __builtin_amdgcn_mfma_f32_16x16x32_bf16(pf, vf, oacc[di], 0, 0, 0);
      }
    }
    __builtin_amdgcn_s_setprio(0);
    __syncthreads();
  }

  float il[4];
#pragma unroll
  for (int r = 0; r < 4; ++r) il[r] = 1.f / __shfl(lrun, ((lane >> 4) << 2) + r);
  const size_t obase = ((size_t)(b * 2048 + q0)) * 2048 + h * 128;
#pragma unroll
  for (int di = 0; di < 8; ++di)
#pragma unroll
    for (int r = 0; r < 4; ++r) {
      const size_t o = obase + (size_t)(((lane >> 4) << 2) + r) * 2048 + (di << 4) + (lane & 15);
      O[o] = f2bf(oacc[di][r] * il[r]);
    }
}

// ---------------------------------------------------------------- launch

extern "C" void kernel_launch(void* const* d_in, const int* in_sizes, int n_in,
                              void* d_out, int out_size, void* d_ws, size_t ws_size,
                              hipStream_t stream) {
  (void)in_sizes; (void)n_in; (void)out_size; (void)ws_size;
  const float* hidden = (const float*)d_in[0];
  const float* ln1_g = (const float*)d_in[1];
  const float* ln1_b = (const float*)d_in[2];
  const float* w_qkv = (const float*)d_in[3];
  const float* b_qkv = (const float*)d_in[4];
  const float* apv = (const float*)d_in[5];
  const float* apg = (const float*)d_in[6];
  const float* apb = (const float*)d_in[7];
  // d_in[8] emotion_bias: softmax-invariant -> dropped (exact)
  const float* ln2_g = (const float*)d_in[9];
  const float* ln2_b = (const float*)d_in[10];
  const float* w_fc = (const float*)d_in[11];
  const float* b_fc = (const float*)d_in[12];
  const float* mpv = (const float*)d_in[13];
  const float* mpg = (const float*)d_in[14];
  const float* mpb = (const float*)d_in[15];

  char* w = (char*)d_ws;
  const size_t MBs = 1ull << 20;
  unsigned short* xln = (unsigned short*)(w + 0);
  float* hidden2 = (float*)(w + 0);
  unsigned short* vtbuf = (unsigned short*)(w + 32 * MBs);
  unsigned short* hbuf = (unsigned short*)(w + 32 * MBs);
  unsigned short* qkv = (unsigned short*)(w + 96 * MBs);
  unsigned short* wfc_bf = (unsigned short*)(w + 96 * MBs);
  unsigned short* partH = (unsigned short*)(w + 96 * MBs);   // 4x16MB bf16 partials
  unsigned short* xln2 = (unsigned short*)(w + 128 * MBs);
  unsigned short* attn_out = (unsigned short*)(w + 144 * MBs);
  unsigned short* wqkv_bf = (unsigned short*)(w + 160 * MBs);
  unsigned short* w2_bf = (unsigned short*)(w + 160 * MBs);
  unsigned short* wproj_bf = (unsigned short*)(w + 192 * MBs);
  float* s_attn = (float*)(w + 200 * MBs);
  float* s_mlp = (float*)(w + 200 * MBs + 32768);
  float* part_attn = (float*)(w + 201 * MBs);
  float* part_mlp = (float*)(w + 202 * MBs);

  hipFuncSetAttribute((const void*)g1_qkv256, hipFuncAttributeMaxDynamicSharedMemorySize, 65536);
  hipFuncSetAttribute((const void*)g3a_fc8p, hipFuncAttributeMaxDynamicSharedMemorySize, 131072);
  hipFuncSetAttribute((const void*)g3b_fc2p, hipFuncAttributeMaxDynamicSharedMemorySize, 65536);
  hipFuncSetAttribute((const void*)g4_splitk256, hipFuncAttributeMaxDynamicSharedMemorySize, 65536);

  // weight prep
  cast_k<<<2048, 256, 0, stream>>>(w_qkv, wqkv_bf, (6144 * 2048) / 4);
  colnorm1_k<<<dim3(4, 32), 256, 0, stream>>>(apv, part_attn, 2048);
  colnorm2_k<<<8, 256, 0, stream>>>(part_attn, apg, s_attn, 2048, 32);
  scale_cast_k<<<2048, 256, 0, stream>>>(apv, s_attn, wproj_bf, 2048, (2048 * 2048) / 4);
  colnorm1_k<<<dim3(16, 32), 256, 0, stream>>>(mpv, part_mlp, 8192);
  colnorm2_k<<<32, 256, 0, stream>>>(part_mlp, mpg, s_mlp, 8192, 32);

  // LN1 -> xln (bf16)
  ln_k<<<4096, 256, 0, stream>>>(hidden, ln1_g, ln1_b, xln);

  // GEMM1 (256^2 2-phase, 384 co-resident blocks): qkv = xln @ w_qkv^T + b
  GemmP p1 = {xln, wqkv_bf, b_qkv, nullptr, nullptr, qkv, 4096, 6144, 2048};
  g1_qkv256<<<384, 512, 65536, stream>>>(p1);

  // V slice of qkv -> V^T
  vtrans_k<<<1024, 256, 0, stream>>>(qkv, vtbuf);

  // attention (QBLK=128, 8 waves) -> attn_out
  attn_k<<<512, 512, 0, stream>>>(qkv, vtbuf, attn_out);

  // weight casts for MLP
  cast_k<<<2048, 256, 0, stream>>>(w_fc, wfc_bf, (8192 * 2048) / 4);
  scale_cast_k<<<4096, 256, 0, stream>>>(mpv, s_mlp, w2_bf, 8192, (2048 * 8192) / 4);

  // GEMM2 (128^2): hidden2 = attn_out @ w_proj^T + b + hidden
  GemmP p2 = {attn_out, wproj_bf, apb, hidden, hidden2, nullptr, 4096, 2048, 2048};
  g2_proj128<<<512, 256, 0, stream>>>(p2);

  // LN2 -> xln2
  ln_k<<<4096, 256, 0, stream>>>(hidden2, ln2_g, ln2_b, xln2);

  // GEMM3 A/B experiment: rows 0-2047 8-phase, rows 2048-4095 2-phase
  GemmP p3 = {xln2, wfc_bf, b_fc, nullptr, nullptr, hbuf, 4096, 8192, 2048};
  g3a_fc8p<<<256, 512, 131072, stream>>>(p3);
  g3b_fc2p<<<256, 512, 65536, stream>>>(p3);

  // GEMM4 (256^2 2-phase split-K4, 512 blocks = 2/CU) -> fused reduce
  GemmP p4 = {hbuf, w2_bf, mpb, nullptr, nullptr, partH, 4096, 2048, 8192};
  g4_splitk256<<<512, 512, 65536, stream>>>(p4);
  g4red_k<<<2048, 256, 0, stream>>>(partH, mpb, hidden2, (float*)d_out,
                                    (4096 * 2048) / 4);
}

// Round 10
// 746.195 us; speedup vs baseline: 1.2036x; 1.1559x over previous
//
#include <hip/hip_runtime.h>
#include <hip/hip_bf16.h>

#define DEVI __device__ __forceinline__

typedef __attribute__((ext_vector_type(8))) __bf16 bf16x8;
typedef __attribute__((ext_vector_type(4))) float f32x4;
typedef __attribute__((ext_vector_type(4))) unsigned short u16x4;
typedef __attribute__((ext_vector_type(8))) unsigned short u16x8;

DEVI unsigned short f2bf(float f) {
  unsigned int u = __float_as_uint(f);
  u += 0x7FFFu + ((u >> 16) & 1u);   // RNE
  return (unsigned short)(u >> 16);
}
DEVI float bf2f(unsigned short u) {
  return __uint_as_float(((unsigned int)u) << 16);
}

#define GLD16(g, l) __builtin_amdgcn_global_load_lds(                      \
    (const __attribute__((address_space(1))) void*)(g),                    \
    (__attribute__((address_space(3))) void*)(l), 16, 0, 0)

// ---------------------------------------------------------------- helpers

__global__ __launch_bounds__(256) void cast_k(const float* __restrict__ in,
                                              unsigned short* __restrict__ out,
                                              int n4) {
  for (int i = blockIdx.x * 256 + threadIdx.x; i < n4; i += gridDim.x * 256) {
    f32x4 v = ((const f32x4*)in)[i];
    u16x4 o;
    o.x = f2bf(v.x); o.y = f2bf(v.y); o.z = f2bf(v.z); o.w = f2bf(v.w);
    ((u16x4*)out)[i] = o;
  }
}

// colnorm phase 1: partial column sumsq over a 64-row x 512-col tile.
__global__ __launch_bounds__(256) void colnorm1_k(const float* __restrict__ v,
                                                  float* __restrict__ part,
                                                  int cols) {
  const int tid = threadIdx.x;
  const int g = tid & 127;
  const int s = tid >> 7;
  const int c0 = blockIdx.x * 512;
  const int r0 = blockIdx.y * 64 + s * 32;
  const float* base = v + (size_t)r0 * cols + c0 + g * 4;
  f32x4 acc = {};
#pragma unroll 4
  for (int i = 0; i < 32; ++i) {
    f32x4 x = *(const f32x4*)(base + (size_t)i * cols);
    acc.x += x.x * x.x; acc.y += x.y * x.y;
    acc.z += x.z * x.z; acc.w += x.w * x.w;
  }
  __shared__ f32x4 red[256];
  red[tid] = acc;
  __syncthreads();
  if (s == 0) {
    f32x4 a = red[tid], b = red[tid + 128];
    f32x4 o;
    o.x = a.x + b.x; o.y = a.y + b.y; o.z = a.z + b.z; o.w = a.w + b.w;
    *(f32x4*)(part + (size_t)blockIdx.y * cols + c0 + g * 4) = o;
  }
}

// colnorm phase 2: s[c] = g[c] * rsqrt(sum_rc part[rc][c])
__global__ __launch_bounds__(256) void colnorm2_k(const float* __restrict__ part,
                                                  const float* __restrict__ g,
                                                  float* __restrict__ s,
                                                  int cols, int nrc) {
  const int c = blockIdx.x * 256 + threadIdx.x;
  float acc = 0.f;
  for (int i = 0; i < nrc; ++i) acc += part[(size_t)i * cols + c];
  s[c] = g[c] * rsqrtf(acc);
}

__global__ __launch_bounds__(256) void scale_cast_k(const float* __restrict__ in,
                                                    const float* __restrict__ s,
                                                    unsigned short* __restrict__ out,
                                                    int cols, int n4) {
  const int cmask4 = (cols >> 2) - 1;
  for (int i = blockIdx.x * 256 + threadIdx.x; i < n4; i += gridDim.x * 256) {
    f32x4 v = ((const f32x4*)in)[i];
    f32x4 sv = ((const f32x4*)s)[i & cmask4];
    u16x4 o;
    o.x = f2bf(v.x * sv.x); o.y = f2bf(v.y * sv.y);
    o.z = f2bf(v.z * sv.z); o.w = f2bf(v.w * sv.w);
    ((u16x4*)out)[i] = o;
  }
}

// LayerNorm: one block per row of 2048 fp32, out bf16
__global__ __launch_bounds__(256) void ln_k(const float* __restrict__ x,
                                            const float* __restrict__ g,
                                            const float* __restrict__ b,
                                            unsigned short* __restrict__ out) {
  const int tid = threadIdx.x, lane = tid & 63, wid = tid >> 6;
  const int row = blockIdx.x;
  const float* xr = x + (size_t)row * 2048;
  f32x4 a0 = ((const f32x4*)xr)[tid];
  f32x4 a1 = ((const f32x4*)xr)[tid + 256];
  float s = a0.x + a0.y + a0.z + a0.w + a1.x + a1.y + a1.z + a1.w;
  float ss = a0.x * a0.x + a0.y * a0.y + a0.z * a0.z + a0.w * a0.w +
             a1.x * a1.x + a1.y * a1.y + a1.z * a1.z + a1.w * a1.w;
#pragma unroll
  for (int m = 1; m < 64; m <<= 1) {
    s += __shfl_xor(s, m);
    ss += __shfl_xor(ss, m);
  }
  __shared__ float red[8];
  if (lane == 0) { red[wid] = s; red[4 + wid] = ss; }
  __syncthreads();
  s = red[0] + red[1] + red[2] + red[3];
  ss = red[4] + red[5] + red[6] + red[7];
  const float mu = s * (1.f / 2048.f);
  const float var = ss * (1.f / 2048.f) - mu * mu;
  const float rs = rsqrtf(var + 1e-5f);
  f32x4 g0 = ((const f32x4*)g)[tid], g1 = ((const f32x4*)g)[tid + 256];
  f32x4 b0 = ((const f32x4*)b)[tid], b1 = ((const f32x4*)b)[tid + 256];
  u16x4 o0, o1;
  o0.x = f2bf((a0.x - mu) * rs * g0.x + b0.x);
  o0.y = f2bf((a0.y - mu) * rs * g0.y + b0.y);
  o0.z = f2bf((a0.z - mu) * rs * g0.z + b0.z);
  o0.w = f2bf((a0.w - mu) * rs * g0.w + b0.w);
  o1.x = f2bf((a1.x - mu) * rs * g1.x + b1.x);
  o1.y = f2bf((a1.y - mu) * rs * g1.y + b1.y);
  o1.z = f2bf((a1.z - mu) * rs * g1.z + b1.z);
  o1.w = f2bf((a1.w - mu) * rs * g1.w + b1.w);
  unsigned short* orow = out + (size_t)row * 2048;
  *(u16x4*)(orow + 4 * tid) = o0;
  *(u16x4*)(orow + 1024 + 4 * tid) = o1;
}

// V transpose: V slice of qkv [4096][6144] -> vt [32][128][2048]
__global__ __launch_bounds__(256) void vtrans_k(const unsigned short* __restrict__ qkv,
                                                unsigned short* __restrict__ vt) {
  __shared__ unsigned short t[64][134];
  const int tid = threadIdx.x;
  const int bh = blockIdx.x >> 5, st = blockIdx.x & 31;
  const int b = bh >> 4, h = bh & 15;
  const unsigned short* vb = qkv + (size_t)(b * 2048 + st * 64) * 6144 + 4096 + h * 128;
#pragma unroll
  for (int i = 0; i < 4; ++i) {
    int f = tid + (i << 8);
    int row = f >> 4, c8 = f & 15;
    u16x8 x = *(const u16x8*)(vb + (size_t)row * 6144 + c8 * 8);
#pragma unroll
    for (int j = 0; j < 4; ++j) {
      unsigned int pk = ((unsigned int)x[2 * j + 1] << 16) | x[2 * j];
      *(unsigned int*)&t[row][c8 * 8 + 2 * j] = pk;
    }
  }
  __syncthreads();
  const int lane = tid & 63, wid = tid >> 6;
  unsigned short* ob = vt + ((size_t)bh << 18) + (st << 6);
#pragma unroll
  for (int j = 0; j < 32; ++j) {
    int d = (wid << 5) + j;
    ob[((size_t)d << 11) + lane] = t[lane][d];
  }
}

// split-K4 reduce: out = sum(bf16 parts 0..3) + bias + res (fp32)
__global__ __launch_bounds__(256) void g4red_k(const unsigned short* __restrict__ parts,
                                               const float* __restrict__ bias,
                                               const float* __restrict__ res,
                                               float* __restrict__ out, int n4) {
  const size_t PS = (size_t)4096 * 2048;
  for (int i = blockIdx.x * 256 + threadIdx.x; i < n4; i += gridDim.x * 256) {
    u16x4 a = ((const u16x4*)(parts))[i];
    u16x4 b = ((const u16x4*)(parts + PS))[i];
    u16x4 c = ((const u16x4*)(parts + 2 * PS))[i];
    u16x4 d = ((const u16x4*)(parts + 3 * PS))[i];
    f32x4 r = ((const f32x4*)res)[i];
    f32x4 bb = ((const f32x4*)bias)[i & 511];
    f32x4 o;
    o.x = bf2f(a.x) + bf2f(b.x) + bf2f(c.x) + bf2f(d.x) + r.x + bb.x;
    o.y = bf2f(a.y) + bf2f(b.y) + bf2f(c.y) + bf2f(d.y) + r.y + bb.y;
    o.z = bf2f(a.z) + bf2f(b.z) + bf2f(c.z) + bf2f(d.z) + r.z + bb.z;
    o.w = bf2f(a.w) + bf2f(b.w) + bf2f(c.w) + bf2f(d.w) + r.w + bb.w;
    ((f32x4*)out)[i] = o;
  }
}

// ---------------------------------------------------------------- GEMM params
struct GemmP {
  const unsigned short* A;
  const unsigned short* B;
  const float* bias;
  const float* res;
  float* outF;
  unsigned short* outH;
  int M, N, K;
};

// ---------------------------------------------------------------- 128^2 GEMM (2-phase)
// +bias +res -> fp32
DEVI void gemm128_body(const GemmP& p, int m0, int n0, int k0, int nk) {
  const int tid = threadIdx.x, lane = tid & 63, wid = tid >> 6;
  const int K = p.K;
  const int wr = wid >> 1, wc = wid & 1;

  __shared__ __align__(16) unsigned short sA[2][4096];
  __shared__ __align__(16) unsigned short sB[2][4096];

  const int c0 = tid, c1 = tid + 256;
  const unsigned short* gA0 = p.A + (size_t)(m0 + (c0 >> 2)) * K + k0 + ((c0 & 3) << 3);
  const unsigned short* gA1 = p.A + (size_t)(m0 + (c1 >> 2)) * K + k0 + ((c1 & 3) << 3);
  const unsigned short* gB0 = p.B + (size_t)(n0 + (c0 >> 2)) * K + k0 + ((c0 & 3) << 3);
  const unsigned short* gB1 = p.B + (size_t)(n0 + (c1 >> 2)) * K + k0 + ((c1 & 3) << 3);
  const int l0 = wid << 9, l1 = (wid << 9) + 2048;

  f32x4 acc[4][4] = {};
  const int arow = (wr << 6) + (lane & 15);
  const int brow = (wc << 6) + (lane & 15);
  const int koff = (lane >> 4) << 3;

#define STAGE128(bufi, t) do { int ko = (t) << 5;       \
    GLD16(gA0 + ko, &sA[bufi][l0]);                     \
    GLD16(gA1 + ko, &sA[bufi][l1]);                     \
    GLD16(gB0 + ko, &sB[bufi][l0]);                     \
    GLD16(gB1 + ko, &sB[bufi][l1]); } while (0)

  STAGE128(0, 0);
  __syncthreads();
  int cur = 0;
  for (int t = 0; t < nk; ++t) {
    if (t + 1 < nk) STAGE128(cur ^ 1, t + 1);
    bf16x8 af[4], bfr[4];
#pragma unroll
    for (int i = 0; i < 4; ++i)
      af[i] = *(const bf16x8*)&sA[cur][(arow + (i << 4)) * 32 + koff];
#pragma unroll
    for (int i = 0; i < 4; ++i)
      bfr[i] = *(const bf16x8*)&sB[cur][(brow + (i << 4)) * 32 + koff];
#pragma unroll
    for (int i = 0; i < 4; ++i)
#pragma unroll
      for (int j = 0; j < 4; ++j)
        acc[i][j] = __builtin_amdgcn_mfma_f32_16x16x32_bf16(af[i], bfr[j], acc[i][j], 0, 0, 0);
    __syncthreads();
    cur ^= 1;
  }
#undef STAGE128

  const int rbase = m0 + (wr << 6) + ((lane >> 4) << 2);
  const int cbase = n0 + (wc << 6) + (lane & 15);
#pragma unroll
  for (int mi = 0; mi < 4; ++mi) {
#pragma unroll
    for (int ni = 0; ni < 4; ++ni) {
      const int col = cbase + (ni << 4);
#pragma unroll
      for (int r = 0; r < 4; ++r) {
        const int row = rbase + (mi << 4) + r;
        const size_t o = (size_t)row * p.N + col;
        p.outF[o] = acc[mi][ni][r] + p.bias[col] + p.res[o];
      }
    }
  }
}

// G2: M=4096,N=2048 -> nbm=32,nbn=16. Region/XCD = 8x8.
__global__ __launch_bounds__(256) void g2_proj128(GemmP p) {
  const int x = blockIdx.x & 7, i = blockIdx.x >> 3;  // i in [0,64)
  const int bm = (x >> 1) * 8 + (i >> 3);
  const int bn = (x & 1) * 8 + (i & 7);
  gemm128_body(p, bm << 7, bn << 7, 0, p.K >> 5);
}

// ---------------------------------------------------------------- 256^2 tile common
DEVI void setup256(const GemmP& p, int m0, int n0, int k0,
                   const unsigned short*& gsA0, const unsigned short*& gsA1,
                   const unsigned short*& gsB0, const unsigned short*& gsB1) {
  const int tid = threadIdx.x;
  int r_[2], c_[2];
#pragma unroll
  for (int j = 0; j < 2; ++j) {
    int d = tid * 16 + j * 8192;
    int w = (d & 1023) ^ (((d >> 9) & 1) << 5);   // st_16x32 involution
    r_[j] = ((d >> 10) << 4) + (w >> 6);
    c_[j] = (w & 63) >> 1;
  }
  gsA0 = p.A + (size_t)(m0 + r_[0]) * p.K + k0 + c_[0];
  gsA1 = p.A + (size_t)(m0 + r_[1]) * p.K + k0 + c_[1];
  gsB0 = p.B + (size_t)(n0 + r_[0]) * p.K + k0 + c_[0];
  gsB1 = p.B + (size_t)(n0 + r_[1]) * p.K + k0 + c_[1];
}

// epilogue: EPI 0 = +bias -> bf16   2 = +bias fast-GELU -> bf16   5 = raw -> bf16
template <int EPI>
DEVI void epi256(const GemmP& p, f32x4 (&acc)[8][4], int m0, int n0,
                 unsigned short* outH) {
  const int lane = threadIdx.x & 63, wid = threadIdx.x >> 6;
  const int wr = wid >> 2, wc = wid & 3;
  const int lr = lane & 15, lk = lane >> 4;
  const int rbase = m0 + wr * 128 + (lk << 2);
  const int cbase = n0 + wc * 64 + lr;
#pragma unroll
  for (int m = 0; m < 8; ++m) {
#pragma unroll
    for (int n = 0; n < 4; ++n) {
      const int col = cbase + (n << 4);
      const float bb = (EPI == 5) ? 0.f : p.bias[col];
#pragma unroll
      for (int r = 0; r < 4; ++r) {
        const int row = rbase + (m << 4) + r;
        float v = acc[m][n][r] + bb;
        if constexpr (EPI == 2) {
          float y = 0.7978845608028654f * (v + 0.044715f * v * v * v);
          float u = __expf(2.f * y);
          v = (y > 40.f) ? v : v * (u / (u + 1.f));
        }
        outH[(size_t)row * p.N + col] = f2bf(v);
      }
    }
  }
}

// ---------------------------------------------------------------- 256^2 2-phase
template <int EPI>
DEVI void gemm2p_body(const GemmP& p, unsigned short* lds_raw, int m0, int n0,
                      int k0, int nk, unsigned short* outH) {
  const int tid = threadIdx.x, lane = tid & 63, wid = tid >> 6;
  const int wr = wid >> 2, wc = wid & 3;
  const int lr = lane & 15, lk = lane >> 4;
  const int fb = (lr * 64 + lk * 16) ^ ((lr & 8) << 2);

  const unsigned short *gsA0, *gsA1, *gsB0, *gsB1;
  setup256(p, m0, n0, k0, gsA0, gsA1, gsB0, gsB1);

#define STG2(b, kt) do { unsigned short* _d = lds_raw + ((b) << 14);     \
    GLD16(gsA0 + ((size_t)(kt) << 5), _d + (tid << 3));                  \
    GLD16(gsA1 + ((size_t)(kt) << 5), _d + 4096 + (tid << 3));           \
    GLD16(gsB0 + ((size_t)(kt) << 5), _d + 8192 + (tid << 3));           \
    GLD16(gsB1 + ((size_t)(kt) << 5), _d + 12288 + (tid << 3)); } while (0)

  f32x4 acc[8][4] = {};
  STG2(0, 0);
  __syncthreads();
  int cur = 0;
  for (int t = 0; t < nk; ++t) {
    if (t + 1 < nk) STG2(cur ^ 1, t + 1);
    const char* tA = (const char*)(lds_raw + (cur << 14));
    const char* tB = tA + 16384;
    bf16x8 a_[8], b_[4];
#pragma unroll
    for (int n = 0; n < 4; ++n)
      b_[n] = *(const bf16x8*)(tB + (((wc << 2) + n) << 10) + fb);
#pragma unroll
    for (int m = 0; m < 8; ++m)
      a_[m] = *(const bf16x8*)(tA + (((wr << 3) + m) << 10) + fb);
#pragma unroll
    for (int m = 0; m < 8; ++m)
#pragma unroll
      for (int n = 0; n < 4; ++n)
        acc[m][n] = __builtin_amdgcn_mfma_f32_16x16x32_bf16(a_[m], b_[n], acc[m][n], 0, 0, 0);
    __syncthreads();
    cur ^= 1;
  }
#undef STG2
  epi256<EPI>(p, acc, m0, n0, outH);
}

// G1 (256^2 2-phase): M=4096,N=6144 -> nbm=16,nbn=24; region 8x6 per XCD.
__global__ __launch_bounds__(512, 2) void g1_qkv256(GemmP p) {
  extern __shared__ unsigned short lds_raw[];
  const int x = blockIdx.x & 7, i = blockIdx.x >> 3;   // i in [0,48)
  const int bm = (x & 1) * 8 + (i & 7);
  const int bn = (x >> 1) * 6 + (i >> 3);
  gemm2p_body<0>(p, lds_raw, bm << 8, bn << 8, 0, p.K >> 5, p.outH);
}
// G3 unified (256^2 2-phase): M=4096,N=8192 -> nbm=16,nbn=32. 512 blocks = 2/CU,
// all co-resident (was two sequential 256-block launches at 1/CU each).
__global__ __launch_bounds__(512, 2) void g3_fc256(GemmP p) {
  extern __shared__ unsigned short lds_raw[];
  const int x = blockIdx.x & 7, i = blockIdx.x >> 3;   // i in [0,64)
  const int bm = (x & 1) * 8 + (i & 7);
  const int bn = (x >> 1) * 8 + (i >> 3);
  gemm2p_body<2>(p, lds_raw, bm << 8, bn << 8, 0, p.K >> 5, p.outH);
}
// G4 (256^2 2-phase, split-K4): nbm=16,nbn=8, ks in [0,4). 512 blocks = 2/CU.
__global__ __launch_bounds__(512, 2) void g4_splitk256(GemmP p) {
  extern __shared__ unsigned short lds_raw[];
  const int x = blockIdx.x & 7, i = blockIdx.x >> 3;   // i in [0,64)
  const int ks = x & 3;
  const int bm = (x >> 2) * 8 + (i >> 3);
  const int bn = i & 7;
  unsigned short* outH = p.outH + (size_t)ks * 4096 * 2048;
  gemm2p_body<5>(p, lds_raw, bm << 8, bn << 8, ks << 11, 64, outH);
}

// ---------------------------------------------------------------- attention
// QBLK=128 (8 waves). Q,K from unified qkv [4096][6144]; V^T [32][128][2048].
// sP stride 72 ushorts (144B = 4 banks/lane shift): all LDS access 2-way max.
__global__ __launch_bounds__(512) void attn_k(const unsigned short* __restrict__ qkv,
                                              const unsigned short* __restrict__ Vt,
                                              unsigned short* __restrict__ O) {
  const int tid = threadIdx.x, lane = tid & 63, wid = tid >> 6;
  const int bid = blockIdx.x;                 // grid = 512
  const int pos = bid >> 3;                   // [0,64)
  const int bh = (bid & 7) * 4 + (pos >> 4);
  const int qt = pos & 15;
  const int q0 = qt * 128 + wid * 16;
  const int b = bh >> 4, h = bh & 15;

  __shared__ __align__(16) unsigned short sK[64 * 128];
  __shared__ __align__(16) unsigned short sV[128 * 64];
  __shared__ __align__(16) unsigned short sP[8][16 * 72];

  const unsigned short* Qb = qkv + (size_t)(b * 2048) * 6144 + h * 128;
  const unsigned short* Kb = qkv + (size_t)(b * 2048) * 6144 + 2048 + h * 128;
  const unsigned short* Vb = Vt + ((size_t)bh << 18);

  bf16x8 qf[4];
  {
    const unsigned short* qp = Qb + (size_t)(q0 + (lane & 15)) * 6144 + ((lane >> 4) << 3);
#pragma unroll
    for (int kk = 0; kk < 4; ++kk) qf[kk] = *(const bf16x8*)(qp + kk * 32);
  }

  int koffs[2], voffs[2];
#pragma unroll
  for (int i = 0; i < 2; ++i) {
    const int c = tid + (i << 9);
    const int kv = c >> 4, jj = c & 15;
    const int js = (jj & 8) | ((jj ^ kv) & 7);
    koffs[i] = kv * 6144 + (js << 3);
    const int d = c >> 3, j2 = c & 7;
    const int js2 = j2 ^ (d & 7);
    voffs[i] = d * 2048 + (js2 << 3);
  }
  u16x8 kreg[2], vreg[2];
  auto PREF = [&](int kt) {
    const int kv0 = kt << 6;
    const unsigned short* kb = Kb + (size_t)kv0 * 6144;
#pragma unroll
    for (int i = 0; i < 2; ++i) {
      kreg[i] = *(const u16x8*)(kb + koffs[i]);
      vreg[i] = *(const u16x8*)(Vb + kv0 + voffs[i]);
    }
  };

  f32x4 oacc[8] = {};
  float mrun = -3e38f, lrun = 0.f;
  PREF(0);

  for (int kt = 0; kt < 32; ++kt) {
#pragma unroll
    for (int i = 0; i < 2; ++i) {
      const int c8 = (tid + (i << 9)) << 3;
      *(u16x8*)&sK[c8] = kreg[i];
      *(u16x8*)&sV[c8] = vreg[i];
    }
    __syncthreads();
    if (kt + 1 < 32) PREF(kt + 1);

    f32x4 sc[4] = {};
    __builtin_amdgcn_s_setprio(1);
#pragma unroll
    for (int ti = 0; ti < 4; ++ti) {
#pragma unroll
      for (int kk = 0; kk < 4; ++kk) {
        const int row = (ti << 4) + (lane & 15);
        int bo = (row << 8) + (kk << 6) + ((lane >> 4) << 4);
        bo ^= (row & 7) << 4;
        bf16x8 kf = *(const bf16x8*)((const char*)sK + bo);
        sc[ti] = __builtin_amdgcn_mfma_f32_16x16x32_bf16(kf, qf[kk], sc[ti], 0, 0, 0);
      }
    }
    __builtin_amdgcn_s_setprio(0);

    float pv[16];
    float mx = -3e38f;
#pragma unroll
    for (int ti = 0; ti < 4; ++ti)
#pragma unroll
      for (int r = 0; r < 4; ++r) {
        float x = sc[ti][r] * 0.08838834764831845f;
        pv[(ti << 2) + r] = x;
        mx = fmaxf(mx, x);
      }
    mx = fmaxf(mx, __shfl_xor(mx, 16));
    mx = fmaxf(mx, __shfl_xor(mx, 32));

    float corr = 1.f;
    if (!__all(mx - mrun <= 8.f)) {
      const float mnew = fmaxf(mrun, mx);
      corr = __expf(mrun - mnew);
      mrun = mnew;
      float fr[4];
#pragma unroll
      for (int r = 0; r < 4; ++r) fr[r] = __shfl(corr, ((lane >> 4) << 2) + r);
#pragma unroll
      for (int di = 0; di < 8; ++di)
#pragma unroll
        for (int r = 0; r < 4; ++r) oacc[di][r] *= fr[r];
    }
    float psum = 0.f;
#pragma unroll
    for (int i2 = 0; i2 < 16; ++i2) {
      float e = __expf(pv[i2] - mrun);
      pv[i2] = e;
      psum += e;
    }
    psum += __shfl_xor(psum, 16);
    psum += __shfl_xor(psum, 32);
    lrun = lrun * corr + psum;

    unsigned short* prow = &sP[wid][(lane & 15) * 72];
#pragma unroll
    for (int ti = 0; ti < 4; ++ti) {
      u16x4 w4;
      w4.x = f2bf(pv[(ti << 2) + 0]);
      w4.y = f2bf(pv[(ti << 2) + 1]);
      w4.z = f2bf(pv[(ti << 2) + 2]);
      w4.w = f2bf(pv[(ti << 2) + 3]);
      *(u16x4*)&prow[(ti << 4) + ((lane >> 4) << 2)] = w4;
    }

    __builtin_amdgcn_s_setprio(1);
#pragma unroll
    for (int di = 0; di < 8; ++di) {
#pragma unroll
      for (int ks = 0; ks < 2; ++ks) {
        bf16x8 pf = *(const bf16x8*)((const char*)&sP[wid][0] +
                                     (lane & 15) * 144 + (ks << 6) + ((lane >> 4) << 4));
        const int dr = (di << 4) + (lane & 15);
        int bo = (dr << 7) + (ks << 6) + ((lane >> 4) << 4);
        bo ^= (dr & 7) << 4;
        bf16x8 vf = *(const bf16x8*)((const char*)sV + bo);
        oacc[di] = __builtin_amdgcn_mfma_f32_16x16x32_bf16(pf, vf, oacc[di], 0, 0, 0);
      }
    }
    __builtin_amdgcn_s_setprio(0);
    __syncthreads();
  }

  float il[4];
#pragma unroll
  for (int r = 0; r < 4; ++r) il[r] = 1.f / __shfl(lrun, ((lane >> 4) << 2) + r);
  const size_t obase = ((size_t)(b * 2048 + q0)) * 2048 + h * 128;
#pragma unroll
  for (int di = 0; di < 8; ++di)
#pragma unroll
    for (int r = 0; r < 4; ++r) {
      const size_t o = obase + (size_t)(((lane >> 4) << 2) + r) * 2048 + (di << 4) + (lane & 15);
      O[o] = f2bf(oacc[di][r] * il[r]);
    }
}

// ---------------------------------------------------------------- launch

extern "C" void kernel_launch(void* const* d_in, const int* in_sizes, int n_in,
                              void* d_out, int out_size, void* d_ws, size_t ws_size,
                              hipStream_t stream) {
  (void)in_sizes; (void)n_in; (void)out_size; (void)ws_size;
  const float* hidden = (const float*)d_in[0];
  const float* ln1_g = (const float*)d_in[1];
  const float* ln1_b = (const float*)d_in[2];
  const float* w_qkv = (const float*)d_in[3];
  const float* b_qkv = (const float*)d_in[4];
  const float* apv = (const float*)d_in[5];
  const float* apg = (const float*)d_in[6];
  const float* apb = (const float*)d_in[7];
  // d_in[8] emotion_bias: softmax-invariant -> dropped (exact)
  const float* ln2_g = (const float*)d_in[9];
  const float* ln2_b = (const float*)d_in[10];
  const float* w_fc = (const float*)d_in[11];
  const float* b_fc = (const float*)d_in[12];
  const float* mpv = (const float*)d_in[13];
  const float* mpg = (const float*)d_in[14];
  const float* mpb = (const float*)d_in[15];

  char* w = (char*)d_ws;
  const size_t MBs = 1ull << 20;
  unsigned short* xln = (unsigned short*)(w + 0);
  float* hidden2 = (float*)(w + 0);
  unsigned short* vtbuf = (unsigned short*)(w + 32 * MBs);
  unsigned short* hbuf = (unsigned short*)(w + 32 * MBs);
  unsigned short* qkv = (unsigned short*)(w + 96 * MBs);
  unsigned short* wfc_bf = (unsigned short*)(w + 96 * MBs);
  unsigned short* partH = (unsigned short*)(w + 96 * MBs);   // 4x16MB bf16 partials
  unsigned short* xln2 = (unsigned short*)(w + 128 * MBs);
  unsigned short* attn_out = (unsigned short*)(w + 144 * MBs);
  unsigned short* wqkv_bf = (unsigned short*)(w + 160 * MBs);
  unsigned short* w2_bf = (unsigned short*)(w + 160 * MBs);
  unsigned short* wproj_bf = (unsigned short*)(w + 192 * MBs);
  float* s_attn = (float*)(w + 200 * MBs);
  float* s_mlp = (float*)(w + 200 * MBs + 32768);
  float* part_attn = (float*)(w + 201 * MBs);
  float* part_mlp = (float*)(w + 202 * MBs);

  hipFuncSetAttribute((const void*)g1_qkv256, hipFuncAttributeMaxDynamicSharedMemorySize, 65536);
  hipFuncSetAttribute((const void*)g3_fc256, hipFuncAttributeMaxDynamicSharedMemorySize, 65536);
  hipFuncSetAttribute((const void*)g4_splitk256, hipFuncAttributeMaxDynamicSharedMemorySize, 65536);

  // weight prep
  cast_k<<<2048, 256, 0, stream>>>(w_qkv, wqkv_bf, (6144 * 2048) / 4);
  colnorm1_k<<<dim3(4, 32), 256, 0, stream>>>(apv, part_attn, 2048);
  colnorm2_k<<<8, 256, 0, stream>>>(part_attn, apg, s_attn, 2048, 32);
  scale_cast_k<<<2048, 256, 0, stream>>>(apv, s_attn, wproj_bf, 2048, (2048 * 2048) / 4);
  colnorm1_k<<<dim3(16, 32), 256, 0, stream>>>(mpv, part_mlp, 8192);
  colnorm2_k<<<32, 256, 0, stream>>>(part_mlp, mpg, s_mlp, 8192, 32);

  // LN1 -> xln (bf16)
  ln_k<<<4096, 256, 0, stream>>>(hidden, ln1_g, ln1_b, xln);

  // GEMM1 (256^2 2-phase, 384 co-resident blocks): qkv = xln @ w_qkv^T + b
  GemmP p1 = {xln, wqkv_bf, b_qkv, nullptr, nullptr, qkv, 4096, 6144, 2048};
  g1_qkv256<<<384, 512, 65536, stream>>>(p1);

  // V slice of qkv -> V^T
  vtrans_k<<<1024, 256, 0, stream>>>(qkv, vtbuf);

  // attention (QBLK=128, 8 waves) -> attn_out
  attn_k<<<512, 512, 0, stream>>>(qkv, vtbuf, attn_out);

  // weight casts for MLP
  cast_k<<<2048, 256, 0, stream>>>(w_fc, wfc_bf, (8192 * 2048) / 4);
  scale_cast_k<<<4096, 256, 0, stream>>>(mpv, s_mlp, w2_bf, 8192, (2048 * 8192) / 4);

  // GEMM2 (128^2): hidden2 = attn_out @ w_proj^T + b + hidden
  GemmP p2 = {attn_out, wproj_bf, apb, hidden, hidden2, nullptr, 4096, 2048, 2048};
  g2_proj128<<<512, 256, 0, stream>>>(p2);

  // LN2 -> xln2
  ln_k<<<4096, 256, 0, stream>>>(hidden2, ln2_g, ln2_b, xln2);

  // GEMM3 unified (256^2 2-phase, 512 blocks = 2/CU co-resident)
  GemmP p3 = {xln2, wfc_bf, b_fc, nullptr, nullptr, hbuf, 4096, 8192, 2048};
  g3_fc256<<<512, 512, 65536, stream>>>(p3);

  // GEMM4 (256^2 2-phase split-K4) -> fused reduce
  GemmP p4 = {hbuf, w2_bf, mpb, nullptr, nullptr, partH, 4096, 2048, 8192};
  g4_splitk256<<<512, 512, 65536, stream>>>(p4);
  g4red_k<<<2048, 256, 0, stream>>>(partH, mpb, hidden2, (float*)d_out,
                                    (4096 * 2048) / 4);
}